// Round 17
// baseline (516.679 us; speedup 1.0000x reference)
//
#include <hip/hip_runtime.h>
#include <cstdint>

#define NPTS 6144
#define CH 96
#define NCELEM (NPTS*CH)
#define HTSZ 16384
#define NBALL 514   // lattice points with 0 < d2 <= 25

// ---------- helpers ----------
__device__ __forceinline__ unsigned fenc(float f){
  unsigned u = __float_as_uint(f);
  return (u & 0x80000000u) ? ~u : (u | 0x80000000u);
}
__device__ __forceinline__ float fdec(unsigned u){
  unsigned b = (u & 0x80000000u) ? (u & 0x7FFFFFFFu) : ~u;
  return __uint_as_float(b);
}
// stats buffers hold (sum, sumsq) doubles per column; convert to (mean, rstd)
__device__ __forceinline__ float2 bnstat(const double* __restrict__ st, int c){
  double mean = st[c*2] / (double)NPTS;
  double var  = st[c*2+1] / (double)NPTS - mean*mean;
  return make_float2((float)mean, (float)(1.0/sqrt(var + 1e-5)));
}

__device__ void eig3(double a00,double a01,double a02,double a11,double a12,double a22,
                     double &e0,double &e1,double &e2){
  double p1 = a01*a01 + a02*a02 + a12*a12;
  double q = (a00+a11+a22)/3.0;
  double b00=a00-q, b11=a11-q, b22=a22-q;
  double p2 = b00*b00 + b11*b11 + b22*b22 + 2.0*p1;
  if (p2 <= 1e-300){ e0=e1=e2=q; return; }
  double pp = sqrt(p2/6.0);
  double inv = 1.0/pp;
  double c00=b00*inv, c01=a01*inv, c02=a02*inv, c11=b11*inv, c12=a12*inv, c22=b22*inv;
  double det = c00*(c11*c22-c12*c12) - c01*(c01*c22-c12*c02) + c02*(c01*c12-c11*c02);
  double r = det*0.5;
  r = r < -1.0 ? -1.0 : (r > 1.0 ? 1.0 : r);
  double phi = acos(r)/3.0;
  e0 = q + 2.0*pp*cos(phi);
  e2 = q + 2.0*pp*cos(phi + 2.0943951023931953);
  e1 = 3.0*q - e0 - e2;
}

// ---------- fused setup 0: all zero/const inits ----------
__global__ void k_setup0(int* __restrict__ zb, long zcount,
                         unsigned long long* __restrict__ htk, int* __restrict__ htv,
                         int* __restrict__ table, int* __restrict__ startmm){
  long i = (long)blockIdx.x*blockDim.x + threadIdx.x;
  long st = (long)gridDim.x*blockDim.x;
  for (long j=i; j<zcount; j+=st) zb[j] = 0;
  for (long j=i; j<3*HTSZ; j+=st){ htk[j] = ~0ull; htv[j] = 0x7fffffff; }
  for (long j=i; j<2*32768; j+=st) table[j] = -1;
  if (i < 3) startmm[i] = 0x7fffffff;
  else if (i < 6) startmm[i] = 0;
}
// ---------- fused setup 1: pack + coord min/max + table fill | ball ----------
__global__ void __launch_bounds__(256) k_setup1(const int* __restrict__ ind,
                                                unsigned* __restrict__ packed,
                                                int* __restrict__ startmm,
                                                int* __restrict__ table,
                                                unsigned* __restrict__ ball){
  __shared__ int mn[3], mx[3];
  __shared__ int hcnt[32], hbase[32], hpos[32];
  int tid = threadIdx.x;
  if (blockIdx.x < 24){
    if (tid < 3){ mn[tid] = 0x7fffffff; mx[tid] = 0; }
    __syncthreads();
    int p = blockIdx.x*256 + tid;
    int b = ind[p*4], z = ind[p*4+1], y = ind[p*4+2], x = ind[p*4+3];
    packed[p] = (unsigned)((b<<15)|(z<<10)|(y<<5)|x);
    table[((b*32+z)*32+y)*32+x] = p;
    atomicMin(&mn[0], z); atomicMin(&mn[1], y); atomicMin(&mn[2], x);
    atomicMax(&mx[0], z); atomicMax(&mx[1], y); atomicMax(&mx[2], x);
    __syncthreads();
    if (tid < 3){
      atomicMin(&startmm[tid], mn[tid]);
      atomicMax(&startmm[3+tid], mx[tid]);
    }
  } else {
    if (tid < 32){ hcnt[tid] = 0; hpos[tid] = 0; }
    __syncthreads();
    for (int i=tid; i<1331; i+=256){
      int dz = i/121, rm = i - dz*121, dy = rm/11, dx = rm - dy*11;
      int a = dz-5, b = dy-5, c = dx-5;
      int d2 = a*a + b*b + c*c;
      if (d2 > 0 && d2 <= 25) atomicAdd(&hcnt[d2], 1);
    }
    __syncthreads();
    if (tid == 0){
      int acc = 0;
      for (int d=1; d<=25; ++d){ hbase[d] = acc; acc += hcnt[d]; }
    }
    __syncthreads();
    for (int i=tid; i<1331; i+=256){
      int dz = i/121, rm = i - dz*121, dy = rm/11, dx = rm - dy*11;
      int a = dz-5, b = dy-5, c = dx-5;
      int d2 = a*a + b*b + c*c;
      if (d2 > 0 && d2 <= 25){
        int pos = hbase[d2] + atomicAdd(&hpos[d2], 1);
        ball[pos] = ((unsigned)d2<<16)|((unsigned)dz<<10)|((unsigned)dy<<5)|(unsigned)dx;
      }
    }
  }
}

// ---------- generic GEMM: O = act(A)@W.T + bias (k-major LDS) ----------
// statsBase: (sum,sumsq) doubles per col for input BN (mode>=1).
// statsumBase: per-zb output (sum,sumsq) accumulator for O's columns.
__global__ void __launch_bounds__(256) k_mm(
    const float* __restrict__ Abase, const float* __restrict__ Wbase,
    const float* __restrict__ biasBase, float* __restrict__ Obase,
    int CIN, int COUT,
    long sA, long sW, long sO, long sBias,
    const double* __restrict__ statsBase, long sStats,
    const float* __restrict__ gBase, const float* __restrict__ beBase, long sGB,
    const float* __restrict__ SsumBase, const int* __restrict__ segBase, const int* __restrict__ cntBase,
    unsigned* maxenc, int mode, double* statsumBase)
{
  int zb = blockIdx.y;
  const float* A = Abase + (long)zb*sA;
  const float* W = Wbase + (long)zb*sW;
  float* O = Obase + (long)zb*sO;
  const double* st = statsBase ? statsBase + (long)zb*sStats : nullptr;
  const float* g  = gBase ? gBase + (long)zb*sGB : nullptr;
  const float* be = beBase ? beBase + (long)zb*sGB : nullptr;
  const float* Ss = SsumBase ? SsumBase + (long)zb*NCELEM : nullptr;
  const int* seg  = segBase ? segBase + (long)zb*NPTS : nullptr;
  const int* cnt  = cntBase ? cntBase + (long)zb*NPTS : nullptr;
  double* ssum = statsumBase ? statsumBase + (long)zb*192 : nullptr;

  __shared__ float Alt[96*34];
  __shared__ float Wlt[96*98];
  __shared__ float lms[192];
  __shared__ float lsum[96], lsq[96];
  int tid = threadIdx.x;
  int r0 = blockIdx.x*32;
  if (tid < 96){ lsum[tid] = 0.f; lsq[tid] = 0.f; }
  if (mode >= 1 && tid < CIN){
    float2 ms = bnstat(st, tid);
    lms[tid*2] = ms.x; lms[tid*2+1] = ms.y;
  }
  __syncthreads();
  for (int idx = tid; idx < CIN*COUT; idx += 256){
    int co = idx / CIN, k = idx - co*CIN;
    Wlt[k*98 + co] = W[idx];
  }
  for (int idx = tid; idx < 32*CIN; idx += 256){
    int ir = idx / CIN, k = idx - ir*CIN;
    int row = r0 + ir;
    float v = A[(long)row*CIN + k];
    if (mode >= 1) v = fmaxf((v - lms[k*2])*lms[k*2+1]*g[k] + be[k], 0.f);
    if (mode == 2){
      int s = seg[row];
      float cf = fmaxf((float)cnt[s], 1.f);
      v -= Ss[(long)s*CH + k] / cf;
    }
    Alt[k*34 + ir] = v;
  }
  __syncthreads();
  float lmax = -3.4e38f;
  if (COUT == 96){
    int rp = tid >> 4, cg = tid & 15;
    int co0 = cg*6;
    float acc0[6], acc1[6];
    #pragma unroll
    for (int j=0;j<6;++j){
      float b = biasBase ? biasBase[(long)zb*sBias + co0 + j] : 0.f;
      acc0[j] = b; acc1[j] = b;
    }
    int ra = 2*rp;
    for (int k=0;k<CIN;++k){
      float2 a  = *(const float2*)&Alt[k*34 + ra];
      float2 w0 = *(const float2*)&Wlt[k*98 + co0];
      float2 w1 = *(const float2*)&Wlt[k*98 + co0 + 2];
      float2 w2 = *(const float2*)&Wlt[k*98 + co0 + 4];
      acc0[0] = fmaf(a.x, w0.x, acc0[0]); acc1[0] = fmaf(a.y, w0.x, acc1[0]);
      acc0[1] = fmaf(a.x, w0.y, acc0[1]); acc1[1] = fmaf(a.y, w0.y, acc1[1]);
      acc0[2] = fmaf(a.x, w1.x, acc0[2]); acc1[2] = fmaf(a.y, w1.x, acc1[2]);
      acc0[3] = fmaf(a.x, w1.y, acc0[3]); acc1[3] = fmaf(a.y, w1.y, acc1[3]);
      acc0[4] = fmaf(a.x, w2.x, acc0[4]); acc1[4] = fmaf(a.y, w2.x, acc1[4]);
      acc0[5] = fmaf(a.x, w2.y, acc0[5]); acc1[5] = fmaf(a.y, w2.y, acc1[5]);
    }
    int rb = ra+1;
    #pragma unroll
    for (int j=0;j<6;++j){
      O[(long)(r0+ra)*96 + co0 + j] = acc0[j];
      O[(long)(r0+rb)*96 + co0 + j] = acc1[j];
      lmax = fmaxf(lmax, fmaxf(acc0[j], acc1[j]));
    }
    if (ssum){
      #pragma unroll
      for (int j=0;j<6;++j){
        atomicAdd(&lsum[co0+j], acc0[j] + acc1[j]);
        atomicAdd(&lsq[co0+j],  acc0[j]*acc0[j] + acc1[j]*acc1[j]);
      }
    }
  } else {
    for (int idx = tid; idx < 32*COUT; idx += 256){
      int ir = idx/COUT, co = idx - ir*COUT;
      float acc = biasBase ? biasBase[(long)zb*sBias + co] : 0.f;
      for (int k=0;k<CIN;++k) acc = fmaf(Alt[k*34+ir], Wlt[k*98+co], acc);
      O[(long)(r0+ir)*COUT + co] = acc;
      lmax = fmaxf(lmax, acc);
      if (ssum){
        atomicAdd(&lsum[co], acc);
        atomicAdd(&lsq[co], acc*acc);
      }
    }
  }
  if (ssum){
    __syncthreads();
    if (tid < COUT){
      atomicAdd(&ssum[tid*2],   (double)lsum[tid]);
      atomicAdd(&ssum[tid*2+1], (double)lsq[tid]);
    }
  }
  if (maxenc){
    __shared__ float rmx[256];
    rmx[tid] = lmax; __syncthreads();
    for (int s2=128; s2>0; s2>>=1){
      if (tid < s2) rmx[tid] = fmaxf(rmx[tid], rmx[tid+s2]);
      __syncthreads();
    }
    if (tid == 0) atomicMax(&maxenc[zb], fenc(rmx[0]));
  }
}

// fused gemm: tf = [relu(bn(tp3)), agg] @ fuse_w.T (CIN=192, COUT=96) + tf col-stats
__global__ void __launch_bounds__(256) k_mm_fuse(
    const float* __restrict__ tp3, const double* __restrict__ st,
    const float* __restrict__ pg3, const float* __restrict__ pbe3,
    const float* __restrict__ agg, const float* __restrict__ fw, float* __restrict__ tf,
    double* __restrict__ tfsum)
{
  __shared__ float Alt[192*34];
  __shared__ float Wlt[96*98];
  __shared__ float lscr[192];   // lms during staging; (lsum,lsq) during flush
  int tid = threadIdx.x, r0 = blockIdx.x*32;
  if (tid < 96){
    float2 ms = bnstat(st, tid);
    lscr[tid*2] = ms.x; lscr[tid*2+1] = ms.y;
  }
  __syncthreads();
  for (int idx = tid; idx < 32*192; idx += 256){
    int ir = idx/192, k = idx - ir*192;
    int row = r0 + ir;
    float v;
    if (k < 96){
      v = tp3[(long)row*96 + k];
      v = fmaxf((v - lscr[k*2])*lscr[k*2+1]*pg3[k] + pbe3[k], 0.f);
    } else {
      v = agg[(long)row*96 + (k-96)];
    }
    Alt[k*34 + ir] = v;
  }
  int rp = tid >> 4, cg = tid & 15, co0 = cg*6;
  float acc0[6] = {0,0,0,0,0,0}, acc1[6] = {0,0,0,0,0,0};
  int ra = 2*rp, rb = ra+1;
  for (int h=0; h<2; ++h){
    __syncthreads();
    for (int idx = tid; idx < 96*96; idx += 256){
      int co = idx/96, k = idx - co*96;
      Wlt[k*98+co] = fw[(long)co*192 + h*96 + k];
    }
    __syncthreads();
    for (int k=0;k<96;++k){
      float2 a  = *(const float2*)&Alt[(h*96 + k)*34 + ra];
      float2 w0 = *(const float2*)&Wlt[k*98 + co0];
      float2 w1 = *(const float2*)&Wlt[k*98 + co0 + 2];
      float2 w2 = *(const float2*)&Wlt[k*98 + co0 + 4];
      acc0[0] = fmaf(a.x, w0.x, acc0[0]); acc1[0] = fmaf(a.y, w0.x, acc1[0]);
      acc0[1] = fmaf(a.x, w0.y, acc0[1]); acc1[1] = fmaf(a.y, w0.y, acc1[1]);
      acc0[2] = fmaf(a.x, w1.x, acc0[2]); acc1[2] = fmaf(a.y, w1.x, acc1[2]);
      acc0[3] = fmaf(a.x, w1.y, acc0[3]); acc1[3] = fmaf(a.y, w1.y, acc1[3]);
      acc0[4] = fmaf(a.x, w2.x, acc0[4]); acc1[4] = fmaf(a.y, w2.x, acc1[4]);
      acc0[5] = fmaf(a.x, w2.y, acc0[5]); acc1[5] = fmaf(a.y, w2.y, acc1[5]);
    }
  }
  #pragma unroll
  for (int j=0;j<6;++j){
    tf[(long)(r0+ra)*96 + co0 + j] = acc0[j];
    tf[(long)(r0+rb)*96 + co0 + j] = acc1[j];
  }
  // column stats of tf: reuse lscr as lsum[0..95] / lsq[96..191]
  __syncthreads();
  if (tid < 96){ lscr[tid] = 0.f; lscr[96+tid] = 0.f; }
  __syncthreads();
  #pragma unroll
  for (int j=0;j<6;++j){
    atomicAdd(&lscr[co0+j],    acc0[j] + acc1[j]);
    atomicAdd(&lscr[96+co0+j], acc0[j]*acc0[j] + acc1[j]*acc1[j]);
  }
  __syncthreads();
  if (tid < 96){
    atomicAdd(&tfsum[tid*2],   (double)lscr[tid]);
    atomicAdd(&tfsum[tid*2+1], (double)lscr[96+tid]);
  }
}

// ---------- column stats (sum, sumsq) over N rows (fallback path only) ----------
__global__ void k_stats(const float* __restrict__ Abase, long sA, int COLS,
                        double* __restrict__ statsBase, long sStats){
  int col = blockIdx.x, zb = blockIdx.y;
  const float* A = Abase + (long)zb*sA;
  double s = 0.0, q = 0.0;
  for (int r = threadIdx.x; r < NPTS; r += 256){
    double v = (double)A[(long)r*COLS + col];
    s += v; q += v*v;
  }
  __shared__ double ls[256], lq[256];
  ls[threadIdx.x] = s; lq[threadIdx.x] = q; __syncthreads();
  for (int t=128; t>0; t>>=1){
    if (threadIdx.x < t){ ls[threadIdx.x] += ls[threadIdx.x+t]; lq[threadIdx.x] += lq[threadIdx.x+t]; }
    __syncthreads();
  }
  if (threadIdx.x == 0){
    double* stp = statsBase + (long)zb*sStats + col*2;
    stp[0] = ls[0];
    stp[1] = lq[0];
  }
}

// ---------- stage A: p = relu(bn(t9)); attention; enh ----------
__global__ void k_p_att_enh(const float* __restrict__ t9, const double* __restrict__ st,
                            const float* __restrict__ fg, const float* __restrict__ fbe,
                            const float* __restrict__ aw1, const float* __restrict__ ab1,
                            const float* __restrict__ aw2, const float* __restrict__ ab2,
                            float* __restrict__ enh){
  __shared__ float lms[18];
  if (threadIdx.x < 9){
    float2 ms = bnstat(st, threadIdx.x);
    lms[threadIdx.x*2] = ms.x; lms[threadIdx.x*2+1] = ms.y;
  }
  __syncthreads();
  int p = blockIdx.x*blockDim.x + threadIdx.x;
  if (p >= NPTS) return;
  float pp[9];
  #pragma unroll
  for (int c=0;c<9;++c){
    float v = t9[p*9+c];
    pp[c] = fmaxf((v - lms[c*2])*lms[c*2+1]*fg[c] + fbe[c], 0.f);
  }
  float eo[9];
  eo[0]=pp[0]; eo[1]=pp[1]; eo[2]=pp[2];
  #pragma unroll
  for (int i=0;i<2;++i){
    const float* w1 = aw1 + i*48;
    const float* b1 = ab1 + i*16;
    const float* w2 = aw2 + i*48;
    const float* b2 = ab2 + i*3;
    const float* f = pp + 3 + i*3;
    float h[16];
    #pragma unroll
    for (int j=0;j<16;++j){
      float s = b1[j];
      #pragma unroll
      for (int k=0;k<3;++k) s = fmaf(f[k], w1[j*3+k], s);
      h[j] = fmaxf(s, 0.f);
    }
    #pragma unroll
    for (int o=0;o<3;++o){
      float s = b2[o];
      #pragma unroll
      for (int j=0;j<16;++j) s = fmaf(h[j], w2[o*16+j], s);
      float a = 1.f/(1.f + expf(-s));
      eo[3+i*3+o] = f[o]*a;
    }
  }
  #pragma unroll
  for (int c=0;c<9;++c) enh[p*9+c] = eo[c];
}

// ---------- sem attention + feat blend (wave per point) ----------
__global__ void __launch_bounds__(256) k_sem_feat(
    const float* __restrict__ fu, const float* __restrict__ x,
    const float* __restrict__ w1, const float* __restrict__ b1,
    const float* __restrict__ w2, const float* __restrict__ b2,
    float* __restrict__ feat){
  int wid = (blockIdx.x*blockDim.x + threadIdx.x) >> 6;
  int lane = threadIdx.x & 63;
  if (wid >= NPTS) return;
  const float* fr = fu + (long)wid*96;
  float partial = 0.f;
  if (lane < 48){
    float h = b1[lane];
    for (int k=0;k<96;++k) h = fmaf(fr[k], w1[lane*96+k], h);
    h = fmaxf(h, 0.f);
    partial = h * w2[lane];
  }
  for (int m=32; m; m>>=1) partial += __shfl_xor(partial, m);
  float sem = 1.f/(1.f + expf(-(partial + b2[0])));
  for (int c=lane; c<96; c+=64){
    float f = fr[c];
    feat[(long)wid*96+c] = f*sem + x[(long)wid*96+c]*(1.f - sem);
  }
}

// ---------- exact KNN + covariance eigen (wave per point) ----------
// Round-14 version: u32 keys, LDS pk staging, sorted ball + early exit.
__global__ void __launch_bounds__(256) k_knn(const unsigned* __restrict__ packed,
                                             const int* __restrict__ table,
                                             const unsigned* __restrict__ ball,
                                             float* __restrict__ density, float* __restrict__ linearity){
  __shared__ unsigned pk[NPTS];
  for (int i=threadIdx.x; i<NPTS; i+=256) pk[i] = packed[i];
  __syncthreads();
  int pid = blockIdx.x*4 + (threadIdx.x>>6);
  int lane = threadIdx.x & 63;
  unsigned mypc = pk[pid];
  int myb = (int)(mypc>>15);
  int mz = (int)((mypc>>10)&31), my_=(int)((mypc>>5)&31), mx_=(int)(mypc&31);
  unsigned s[16];
  #pragma unroll
  for (int t=0;t<16;++t) s[t] = 0xFFFFFFFFu;
  int cnt = 0;
  const int tbase = myb*32768;
  for (int it=0; it<9; ++it){
    int i = lane + it*64;
    if (i < NBALL){
      unsigned e = ball[i];
      int d2 = (int)(e >> 16);
      int dz = (int)((e>>10)&31) - 5;
      int dy = (int)((e>>5)&31) - 5;
      int dx = (int)(e&31) - 5;
      int zz = mz+dz, yy = my_+dy, xx = mx_+dx;
      if ((unsigned)zz < 32u && (unsigned)yy < 32u && (unsigned)xx < 32u){
        int j = table[tbase + (zz*32+yy)*32+xx];
        if (j >= 0){
          ++cnt;
          unsigned key = ((unsigned)d2<<13) | (unsigned)j;
          if (key < s[15]){
            s[15] = key;
            #pragma unroll
            for (int t=15;t>0;--t){
              unsigned a = s[t-1], b = s[t];
              unsigned lo = a<b?a:b, hi = a<b?b:a;
              s[t-1]=lo; s[t]=hi;
            }
          }
        }
      }
    }
    int nxt = (it+1)*64;
    if (nxt >= NBALL) break;
    int tot = cnt;
    for (int m=32; m; m>>=1) tot += __shfl_xor(tot, m);
    unsigned dlast = ball[nxt-1] >> 16;
    unsigned dnext = ball[nxt] >> 16;
    if (tot >= 16 && dnext > dlast) break;
  }
  int tot = cnt;
  for (int m=32; m; m>>=1) tot += __shfl_xor(tot, m);
  if (tot < 16){
    #pragma unroll
    for (int t=0;t<16;++t) s[t] = 0xFFFFFFFFu;
    for (int it=0; it<96; ++it){
      int j = lane + it*64;
      unsigned pc = pk[j];
      if (j != pid && (int)(pc>>15) == myb){
        int dz = (int)((pc>>10)&31) - mz;
        int dy = (int)((pc>>5)&31) - my_;
        int dx = (int)(pc&31) - mx_;
        unsigned d2 = (unsigned)(dz*dz + dy*dy + dx*dx);
        unsigned key = (d2<<13) | (unsigned)j;
        if (key < s[15]){
          s[15] = key;
          #pragma unroll
          for (int t=15;t>0;--t){
            unsigned a = s[t-1], b = s[t];
            unsigned lo = a<b?a:b, hi = a<b?b:a;
            s[t-1]=lo; s[t]=hi;
          }
        }
      }
    }
  }
  float sdist = 0.f;
  int sz=0,sy=0,sx=0,szz=0,syy=0,sxx=0,szy=0,szx=0,syx=0;
  for (int r=0;r<16;++r){
    unsigned m = s[0];
    #pragma unroll
    for (int w=32; w; w>>=1){
      unsigned o = (unsigned)__shfl_xor((int)m, w);
      m = m<o ? m : o;
    }
    bool own = (s[0] == m);
    #pragma unroll
    for (int t=0;t<15;++t) s[t] = own ? s[t+1] : s[t];
    if (own) s[15] = 0xFFFFFFFFu;
    unsigned idx = m & 8191u;
    unsigned d2 = m >> 13;
    sdist += sqrtf((float)d2);
    unsigned pc = pk[idx];
    int nz=(int)((pc>>10)&31), ny=(int)((pc>>5)&31), nx=(int)(pc&31);
    sz+=nz; sy+=ny; sx+=nx;
    szz+=nz*nz; syy+=ny*ny; sxx+=nx*nx; szy+=nz*ny; szx+=nz*nx; syx+=ny*nx;
  }
  if (lane == 0){
    double m0 = sz/16.0, m1 = sy/16.0, m2 = sx/16.0;
    float c00 = (float)(((double)szz - 16.0*m0*m0)/15.0);
    float c11 = (float)(((double)syy - 16.0*m1*m1)/15.0);
    float c22 = (float)(((double)sxx - 16.0*m2*m2)/15.0);
    float c01 = (float)(((double)szy - 16.0*m0*m1)/15.0);
    float c02 = (float)(((double)szx - 16.0*m0*m2)/15.0);
    float c12 = (float)(((double)syx - 16.0*m1*m2)/15.0);
    double e0,e1,e2;
    eig3((double)c00,(double)c01,(double)c02,(double)c11,(double)c12,(double)c22, e0,e1,e2);
    float s0 = (float)fabs(e0), s1 = (float)fabs(e1), s2 = (float)fabs(e2);
    float den = s0 + s1 + s2 + 1e-6f;
    float sn0 = s0/den, sn1 = s1/den, sn2 = s2/den;
    linearity[pid] = sn0 - (sn1 + sn2);
    float md = sdist * (1.f/16.f);
    density[pid] = 1.f/(md + 1e-6f);
  }
}

// ---------- geometry head ----------
__global__ void k_geo(const float* __restrict__ t64, const double* __restrict__ st,
                      const float* __restrict__ fg, const float* __restrict__ fbe,
                      const float* __restrict__ w2, const float* __restrict__ b2,
                      const float* __restrict__ density, const float* __restrict__ linearity,
                      float* __restrict__ gsz, float* __restrict__ gm){
  __shared__ float lms[128];
  if (threadIdx.x < 64){
    float2 ms = bnstat(st, threadIdx.x);
    lms[threadIdx.x*2] = ms.x; lms[threadIdx.x*2+1] = ms.y;
  }
  __syncthreads();
  int p = blockIdx.x*blockDim.x + threadIdx.x;
  if (p >= NPTS) return;
  float fl[3];
  #pragma unroll
  for (int o=0;o<3;++o) fl[o] = b2[o];
  for (int k=0;k<64;++k){
    float v = t64[(long)p*64+k];
    v = fmaxf((v - lms[k*2])*lms[k*2+1]*fg[k] + fbe[k], 0.f);
    #pragma unroll
    for (int o=0;o<3;++o) fl[o] = fmaf(v, w2[o*64+k], fl[o]);
  }
  float mx = fmaxf(fl[0], fmaxf(fl[1], fl[2]));
  float e0 = expf(fl[0]-mx), e1 = expf(fl[1]-mx), e2 = expf(fl[2]-mx);
  float es = e0+e1+e2;
  float p0 = e0/es, p1 = e1/es, p2 = e2/es;
  float den = density[p], lin = linearity[p];
  float tw = (den*2.f + p0)/3.f;
  float bg = (fmaxf(1.f-lin, 1.f-den) + p1)/3.f;
  float ln = (lin*2.f + p2)/3.f;
  float g0 = tw*0.1f + bg*0.4f + ln*0.2f + 1e-6f;
  float g1 = tw*0.1f + bg*0.4f + ln*0.2f + 1e-6f;
  float g2 = tw*0.1f + bg*0.4f + ln*1.0f + 1e-6f;
  gsz[p*3+0]=g0; gsz[p*3+1]=g1; gsz[p*3+2]=g2;
  gm[p] = (g0+g1+g2)/3.f;
}

// ---------- rank-by-counting ----------
#define RNKCHUNK 768
__global__ void __launch_bounds__(256) k_rank(const float* __restrict__ gm, int* __restrict__ rank){
  __shared__ unsigned long long lk[RNKCHUNK];
  int j0 = blockIdx.y*RNKCHUNK;
  for (int i=threadIdx.x; i<RNKCHUNK; i+=256){
    int j = j0 + i;
    lk[i] = (((unsigned long long)fenc(gm[j]))<<13) | (unsigned long long)j;
  }
  __syncthreads();
  int p = blockIdx.x*256 + threadIdx.x;
  unsigned long long myk = (((unsigned long long)fenc(gm[p]))<<13) | (unsigned long long)p;
  int cnt = 0;
  #pragma unroll 4
  for (int i=0; i<RNKCHUNK; ++i) cnt += (lk[i] < myk) ? 1 : 0;
  atomicAdd(&rank[p], cnt);
}
// scatter + last-block reps (fused)
__global__ void __launch_bounds__(256) k_scatter_reps(const int* __restrict__ rank,
                                                      const float* __restrict__ gsz,
                                                      float* __restrict__ bkt,
                                                      int* __restrict__ done,
                                                      float* __restrict__ reps){
  __shared__ int lastf;
  int p = blockIdx.x*256 + threadIdx.x;
  int r = rank[p];
  int zb = -1, t = 0;
  if (r < 100){ zb = 2; t = r; }
  else if (r < 200){ zb = 0; t = r - 100; }
  else if (r >= NPTS-100){ zb = 1; t = r - (NPTS-100); }
  if (zb >= 0){
    #pragma unroll
    for (int d=0; d<3; ++d) bkt[(zb*100 + t)*3 + d] = gsz[p*3+d];
  }
  __threadfence();
  __syncthreads();
  if (threadIdx.x == 0) lastf = (atomicAdd(done, 1) == 23) ? 1 : 0;
  __syncthreads();
  if (lastf){
    __threadfence();
    int i = threadIdx.x;
    if (i < 9){
      int z = i/3, d = i - z*3;
      double s = 0.0;
      for (int tt=0; tt<100; ++tt) s += (double)bkt[(z*100 + tt)*3 + d];
      reps[i] = (float)(s/100.0);
    }
  }
}

// ---------- cluster id (inlined into seg_build/seg_lookup) ----------
__device__ __forceinline__ unsigned long long cluster_id(
    const int* __restrict__ ind, const float* __restrict__ reps,
    const int* __restrict__ startmm, int z, int p){
  long long mxp[3]; int cc[3];
  #pragma unroll
  for (int d=0; d<3; ++d){
    float sizev = fmaxf(reps[z*3+d], 1e-6f);
    float cf = floorf(((float)ind[p*4+1+d] - (float)startmm[d]) / sizev);
    int ci = (int)cf;
    ci = ci < 0 ? 0 : (ci > 4095 ? 4095 : ci);
    cc[d] = ci;
    float cfm = floorf(((float)startmm[3+d] - (float)startmm[d]) / sizev);
    int cm = (int)cfm;
    cm = cm < 0 ? 0 : (cm > 4095 ? 4095 : cm);
    mxp[d] = (long long)cm + 1;
  }
  long long b = ind[p*4];
  return (unsigned long long)(((b*mxp[0] + cc[0])*mxp[1] + cc[1])*mxp[2] + cc[2]);
}

// ---------- segment labels via hash table ----------
__device__ __forceinline__ int ht_hash(unsigned long long id){
  unsigned long long h = id * 0x9E3779B97F4A7C15ull;
  return (int)(h >> 49) & (HTSZ-1);
}
__global__ void k_seg_build(const int* __restrict__ ind, const float* __restrict__ reps,
                            const int* __restrict__ startmm,
                            unsigned long long* __restrict__ keys, int* __restrict__ vals){
  int z = blockIdx.y;
  int p = blockIdx.x*blockDim.x + threadIdx.x;
  if (p >= NPTS) return;
  unsigned long long id = cluster_id(ind, reps, startmm, z, p);
  unsigned long long* K = keys + (long)z*HTSZ;
  int* V = vals + (long)z*HTSZ;
  int slot = ht_hash(id);
  while (true){
    unsigned long long prev = atomicCAS(&K[slot], ~0ull, id);
    if (prev == ~0ull || prev == id){ atomicMin(&V[slot], p); break; }
    slot = (slot + 1) & (HTSZ-1);
  }
}
__global__ void k_seg_lookup(const int* __restrict__ ind, const float* __restrict__ reps,
                             const int* __restrict__ startmm,
                             const unsigned long long* __restrict__ keys, const int* __restrict__ vals,
                             int* __restrict__ seg, int* __restrict__ cnt){
  int z = blockIdx.y;
  int p = blockIdx.x*blockDim.x + threadIdx.x;
  if (p >= NPTS) return;
  unsigned long long id = cluster_id(ind, reps, startmm, z, p);
  const unsigned long long* K = keys + (long)z*HTSZ;
  int slot = ht_hash(id);
  while (K[slot] != id) slot = (slot + 1) & (HTSZ-1);
  int rep = vals[(long)z*HTSZ + slot];
  seg[(long)z*NPTS + p] = rep;
  atomicAdd(&cnt[(long)z*NPTS + rep], 1);
}

// ---------- branch segment ops ----------
__global__ void k_pw_accum(const float* __restrict__ tlw, const double* __restrict__ stats,
                           const float* __restrict__ g, const float* __restrict__ be,
                           const int* __restrict__ seg, float* __restrict__ S){
  int z = blockIdx.y;
  __shared__ float lms[192];
  if (threadIdx.x < 96){
    float2 ms = bnstat(stats + (long)z*192, threadIdx.x);
    lms[threadIdx.x*2] = ms.x; lms[threadIdx.x*2+1] = ms.y;
  }
  __syncthreads();
  int idx = blockIdx.x*blockDim.x + threadIdx.x;
  int p = idx/CH, c = idx - p*CH;
  float v = tlw[(long)z*NCELEM + idx];
  v = fmaxf((v - lms[c*2])*lms[c*2+1]*g[z*CH+c] + be[z*CH+c], 0.f);
  atomicAdd(&S[(long)z*NCELEM + (long)seg[(long)z*NPTS+p]*CH + c], v);
}
__global__ void k_exp_accum(const float* __restrict__ pw2, const unsigned* __restrict__ maxenc,
                            const int* __restrict__ seg, float* __restrict__ E){
  int z = blockIdx.y;
  int idx = blockIdx.x*blockDim.x + threadIdx.x;
  int p = idx/CH, c = idx - p*CH;
  float mv = fdec(maxenc[z]);
  float v = expf(pw2[(long)z*NCELEM + idx] - mv);
  atomicAdd(&E[(long)z*NCELEM + (long)seg[(long)z*NPTS+p]*CH + c], v);
}
__global__ void k_pf_accum(const float* __restrict__ tp, const double* __restrict__ stats,
                           const float* __restrict__ pg, const float* __restrict__ pbe,
                           const float* __restrict__ pw2, const unsigned* __restrict__ maxenc,
                           const int* __restrict__ seg, const float* __restrict__ E,
                           float* __restrict__ F){
  int z = blockIdx.y;
  __shared__ float lms[192];
  if (threadIdx.x < 96){
    float2 ms = bnstat(stats + (long)z*192, threadIdx.x);
    lms[threadIdx.x*2] = ms.x; lms[threadIdx.x*2+1] = ms.y;
  }
  __syncthreads();
  int idx = blockIdx.x*blockDim.x + threadIdx.x;
  int p = idx/CH, c = idx - p*CH;
  float v = tp[(long)z*NCELEM + idx];
  v = fmaxf((v - lms[c*2])*lms[c*2+1]*pg[z*CH+c] + pbe[z*CH+c], 0.f);
  float mv = fdec(maxenc[z]);
  int sg = seg[(long)z*NPTS+p];
  float w = expf(pw2[(long)z*NCELEM + idx] - mv) / (E[(long)z*NCELEM + (long)sg*CH + c] + 1e-6f);
  atomicAdd(&F[(long)z*NCELEM + (long)sg*CH + c], v*w);
}
// adp softmax + agg gather (fused)
__global__ void __launch_bounds__(256) k_adp_agg(
    const float* __restrict__ feat, const float* __restrict__ aw,
    const float* __restrict__ F, const int* __restrict__ seg,
    float* __restrict__ agg){
  __shared__ float ladp[32][3];
  __shared__ int lseg[32][3];
  int tid = threadIdx.x;
  int p0 = blockIdx.x*32;
  if (tid < 96){
    int pl = tid/3, z = tid - pl*3;
    const float* fr = feat + (long)(p0+pl)*CH;
    float a = 0.f;
    for (int k=0;k<CH;++k) a = fmaf(fr[k], aw[z*CH+k], a);
    ladp[pl][z] = a;
    lseg[pl][z] = seg[(long)z*NPTS + (p0+pl)];
  }
  __syncthreads();
  if (tid < 32){
    float a0 = ladp[tid][0], a1 = ladp[tid][1], a2 = ladp[tid][2];
    float m = fmaxf(a0, fmaxf(a1,a2));
    float e0 = expf(a0-m), e1 = expf(a1-m), e2 = expf(a2-m);
    float s = e0+e1+e2;
    ladp[tid][0]=e0/s; ladp[tid][1]=e1/s; ladp[tid][2]=e2/s;
  }
  __syncthreads();
  for (int e = tid; e < 32*CH; e += 256){
    int pl = e/CH, c = e - pl*CH;
    float s = 0.f;
    #pragma unroll
    for (int z=0;z<3;++z)
      s = fmaf(ladp[pl][z], F[(long)z*NCELEM + (long)lseg[pl][z]*CH + c], s);
    agg[(long)p0*CH + e] = s;
  }
}

// ---------- fallback elementwise (unfused path only) ----------
__global__ void k_zero(int* p, long n){
  long i = (long)blockIdx.x*blockDim.x + threadIdx.x;
  long st = (long)gridDim.x*blockDim.x;
  for (; i < n; i += st) p[i] = 0;
}
__global__ void k_fused(const float* __restrict__ tf, const double* __restrict__ st,
                        const float* __restrict__ fg, const float* __restrict__ fbe,
                        const float* __restrict__ feat, float* __restrict__ fused){
  int idx = blockIdx.x*blockDim.x + threadIdx.x;
  int c = idx % CH;
  float2 ms = bnstat(st, c);
  float v = tf[idx];
  v = fmaxf((v - ms.x)*ms.y*fg[c] + fbe[c], 0.f);
  fused[idx] = v + feat[idx];
}
__global__ void k_bnrelu(const float* __restrict__ a, const double* __restrict__ st,
                         const float* __restrict__ g, const float* __restrict__ be,
                         float* __restrict__ o){
  int idx = blockIdx.x*blockDim.x + threadIdx.x;
  int c = idx % CH;
  float2 ms = bnstat(st, c);
  float v = a[idx];
  o[idx] = fmaxf((v - ms.x)*ms.y*g[c] + be[c], 0.f);
}

// ---------- conv tail ----------
__global__ void __launch_bounds__(256) k_nbrlist(const int* __restrict__ ind,
                                                 const int* __restrict__ table,
                                                 int* __restrict__ nbrtab,
                                                 int* __restrict__ tapcnt,
                                                 int* __restrict__ ptlist){
  __shared__ int pb[256], pz[256], py[256], px[256];
  __shared__ int lcnt[27], lbase[27], lpos[27];
  int tid = threadIdx.x;
  if (tid < 27){ lcnt[tid] = 0; lpos[tid] = 0; }
  int p0 = blockIdx.x*256;
  pb[tid] = ind[(p0+tid)*4];
  pz[tid] = ind[(p0+tid)*4+1];
  py[tid] = ind[(p0+tid)*4+2];
  px[tid] = ind[(p0+tid)*4+3];
  __syncthreads();
  int base = blockIdx.x*6912;
  int qv[27];
  #pragma unroll 1
  for (int j = 0; j < 27; ++j){
    int i = tid + j*256;
    int pl = i/27, tap = i - pl*27;
    int dz = tap/9 - 1;
    int rm = tap % 9;
    int dy = rm/3 - 1, dx = rm%3 - 1;
    int z = pz[pl]+dz, y = py[pl]+dy, x = px[pl]+dx;
    int q = -1;
    if ((unsigned)z < 32u && (unsigned)y < 32u && (unsigned)x < 32u)
      q = table[((pb[pl]*32+z)*32+y)*32+x];
    qv[j] = q;
    nbrtab[base + i] = q;
    if (q >= 0) atomicAdd(&lcnt[tap], 1);
  }
  __syncthreads();
  if (tid < 27) lbase[tid] = atomicAdd(&tapcnt[tid], lcnt[tid]);
  __syncthreads();
  #pragma unroll 1
  for (int j = 0; j < 27; ++j){
    int q = qv[j];
    if (q >= 0){
      int i = tid + j*256;
      int tap = i % 27;
      int p = p0 + i/27;
      int pos = lbase[tap] + atomicAdd(&lpos[tap], 1);
      ptlist[tap*NPTS + pos] = (p<<16) | q;
    }
  }
}
// per-tap gather-GEMM with optional fused BN(+res) on staging; plain stores
__global__ void __launch_bounds__(256) k_conv_gemm(
    const float* __restrict__ src, const float* __restrict__ Wc,
    const int* __restrict__ tapcnt, const int* __restrict__ ptlist,
    const double* __restrict__ bnst, const float* __restrict__ bng,
    const float* __restrict__ bnbe, const float* __restrict__ res,
    int fmode, float* __restrict__ part){
  int tap = blockIdx.y;
  int n = tapcnt[tap];
  int r0 = blockIdx.x*32;
  if (r0 >= n) return;
  __shared__ float Alt[96*34];
  __shared__ float Wlt[96*98];
  __shared__ float lms[192];
  __shared__ int pqs[32];
  int tid = threadIdx.x;
  if (tid < 32){
    int r = r0 + tid;
    pqs[tid] = (r < n) ? ptlist[tap*NPTS + r] : -1;
  }
  if (fmode && tid < 96){
    float2 ms = bnstat(bnst, tid);
    lms[tid*2] = ms.x; lms[tid*2+1] = ms.y;
  }
  __syncthreads();
  for (int idx4 = tid; idx4 < 2304; idx4 += 256){
    int ci = idx4/24, c4 = idx4 - ci*24;
    float4 w = ((const float4*)(Wc + ((long)tap*96 + ci)*96))[c4];
    float* d = &Wlt[ci*98 + c4*4];
    d[0]=w.x; d[1]=w.y; d[2]=w.z; d[3]=w.w;
  }
  for (int idx4 = tid; idx4 < 32*24; idx4 += 256){
    int ir = idx4/24, c4 = idx4 - ir*24;
    int pq = pqs[ir];
    float4 s4 = make_float4(0.f,0.f,0.f,0.f);
    if (pq >= 0){
      int q = pq & 0xFFFF;
      s4 = ((const float4*)(src + (long)q*CH))[c4];
      if (fmode){
        int c0 = c4*4;
        float vx = fmaxf((s4.x - lms[(c0+0)*2])*lms[(c0+0)*2+1]*bng[c0+0] + bnbe[c0+0], 0.f);
        float vy = fmaxf((s4.y - lms[(c0+1)*2])*lms[(c0+1)*2+1]*bng[c0+1] + bnbe[c0+1], 0.f);
        float vz = fmaxf((s4.z - lms[(c0+2)*2])*lms[(c0+2)*2+1]*bng[c0+2] + bnbe[c0+2], 0.f);
        float vw = fmaxf((s4.w - lms[(c0+3)*2])*lms[(c0+3)*2+1]*bng[c0+3] + bnbe[c0+3], 0.f);
        if (fmode == 2){
          const float* rr = res + (long)q*CH + c0;
          vx += rr[0]; vy += rr[1]; vz += rr[2]; vw += rr[3];
        }
        s4 = make_float4(vx,vy,vz,vw);
      }
    }
    int k0 = c4*4;
    Alt[(k0+0)*34 + ir] = s4.x;
    Alt[(k0+1)*34 + ir] = s4.y;
    Alt[(k0+2)*34 + ir] = s4.z;
    Alt[(k0+3)*34 + ir] = s4.w;
  }
  __syncthreads();
  int rp = tid >> 4, cg = tid & 15;
  int co0 = cg*6;
  int ra = 2*rp, rb = ra+1;
  float acc0[6]={0,0,0,0,0,0}, acc1[6]={0,0,0,0,0,0};
  for (int k=0;k<96;++k){
    float2 a  = *(const float2*)&Alt[k*34 + ra];
    float2 w0 = *(const float2*)&Wlt[k*98 + co0];
    float2 w1 = *(const float2*)&Wlt[k*98 + co0 + 2];
    float2 w2 = *(const float2*)&Wlt[k*98 + co0 + 4];
    acc0[0] = fmaf(a.x, w0.x, acc0[0]); acc1[0] = fmaf(a.y, w0.x, acc1[0]);
    acc0[1] = fmaf(a.x, w0.y, acc0[1]); acc1[1] = fmaf(a.y, w0.y, acc1[1]);
    acc0[2] = fmaf(a.x, w1.x, acc0[2]); acc1[2] = fmaf(a.y, w1.x, acc1[2]);
    acc0[3] = fmaf(a.x, w1.y, acc0[3]); acc1[3] = fmaf(a.y, w1.y, acc1[3]);
    acc0[4] = fmaf(a.x, w2.x, acc0[4]); acc1[4] = fmaf(a.y, w2.x, acc1[4]);
    acc0[5] = fmaf(a.x, w2.y, acc0[5]); acc1[5] = fmaf(a.y, w2.y, acc1[5]);
  }
  int pa = pqs[ra], pb2 = pqs[rb];
  if (pa >= 0){
    float* o = part + ((long)(pa>>16)*27 + tap)*CH + co0;
    #pragma unroll
    for (int j=0;j<6;++j) o[j] = acc0[j];
  }
  if (pb2 >= 0){
    float* o = part + ((long)(pb2>>16)*27 + tap)*CH + co0;
    #pragma unroll
    for (int j=0;j<6;++j) o[j] = acc1[j];
  }
}
// gather-sum of per-tap partials + fused column stats of the output
__global__ void __launch_bounds__(256) k_conv_sum(const int* __restrict__ nbrtab,
                                                  const float* __restrict__ part,
                                                  float* __restrict__ out,
                                                  double* __restrict__ csum){
  __shared__ float lsum[96], lsq[96];
  int tid = threadIdx.x;
  if (tid < 96){ lsum[tid] = 0.f; lsq[tid] = 0.f; }
  __syncthreads();
  int idx = blockIdx.x*256 + tid;   // NPTS*24
  int p = idx/24, c4 = idx - p*24;
  const int* nt = nbrtab + p*27;
  float4 acc = make_float4(0.f,0.f,0.f,0.f);
  for (int tap=0; tap<27; ++tap){
    if (nt[tap] >= 0){
      float4 v = ((const float4*)part)[((long)p*27 + tap)*24 + c4];
      acc.x += v.x; acc.y += v.y; acc.z += v.z; acc.w += v.w;
    }
  }
  ((float4*)out)[idx] = acc;
  int c0 = c4*4;
  atomicAdd(&lsum[c0+0], acc.x); atomicAdd(&lsq[c0+0], acc.x*acc.x);
  atomicAdd(&lsum[c0+1], acc.y); atomicAdd(&lsq[c0+1], acc.y*acc.y);
  atomicAdd(&lsum[c0+2], acc.z); atomicAdd(&lsq[c0+2], acc.z*acc.z);
  atomicAdd(&lsum[c0+3], acc.w); atomicAdd(&lsq[c0+3], acc.w*acc.w);
  __syncthreads();
  if (tid < 96){
    atomicAdd(&csum[tid*2],   (double)lsum[tid]);
    atomicAdd(&csum[tid*2+1], (double)lsq[tid]);
  }
}
// fallback: atomic scatter conv
__global__ void __launch_bounds__(256) k_conv_gemm_atomic(
    const float* __restrict__ src, const float* __restrict__ Wc,
    const int* __restrict__ tapcnt, const int* __restrict__ ptlist,
    float* __restrict__ out){
  int tap = blockIdx.y;
  int n = tapcnt[tap];
  int r0 = blockIdx.x*32;
  if (r0 >= n) return;
  __shared__ float Al[32*97];
  __shared__ float Wl[96*97];
  __shared__ int pqs[32];
  int tid = threadIdx.x;
  if (tid < 32){
    int r = r0 + tid;
    pqs[tid] = (r < n) ? ptlist[tap*NPTS + r] : -1;
  }
  __syncthreads();
  for (int idx4 = tid; idx4 < 2304; idx4 += 256){
    int ci = idx4/24, c4 = idx4 - ci*24;
    float4 w = ((const float4*)(Wc + ((long)tap*96 + ci)*96))[c4];
    float* d = &Wl[ci*97 + c4*4];
    d[0]=w.x; d[1]=w.y; d[2]=w.z; d[3]=w.w;
  }
  for (int idx4 = tid; idx4 < 32*24; idx4 += 256){
    int ir = idx4/24, c4 = idx4 - ir*24;
    int pq = pqs[ir];
    float4 s = make_float4(0.f,0.f,0.f,0.f);
    if (pq >= 0){
      int q = pq & 0xFFFF;
      s = ((const float4*)(src + (long)q*CH))[c4];
    }
    float* d = &Al[ir*97 + c4*4];
    d[0]=s.x; d[1]=s.y; d[2]=s.z; d[3]=s.w;
  }
  __syncthreads();
  int rp = tid >> 4, cg = tid & 15;
  int co0 = cg*6;
  int ra = 2*rp, rb = ra+1;
  float acc0[6]={0,0,0,0,0,0}, acc1[6]={0,0,0,0,0,0};
  for (int k=0;k<96;++k){
    float a0 = Al[ra*97+k], a1 = Al[rb*97+k];
    #pragma unroll
    for (int j=0;j<6;++j){
      float w = Wl[k*97+co0+j];
      acc0[j] = fmaf(a0, w, acc0[j]);
      acc1[j] = fmaf(a1, w, acc1[j]);
    }
  }
  int pa = pqs[ra], pb = pqs[rb];
  if (pa >= 0){
    float* o = out + (long)(pa>>16)*CH + co0;
    #pragma unroll
    for (int j=0;j<6;++j) atomicAdd(&o[j], acc0[j]);
  }
  if (pb >= 0){
    float* o = out + (long)(pb>>16)*CH + co0;
    #pragma unroll
    for (int j=0;j<6;++j) atomicAdd(&o[j], acc1[j]);
  }
}
// final: recompute fsd inline + bn2 + residual relu
__global__ void k_final(const float* __restrict__ c2, const double* __restrict__ st12,
                        const float* __restrict__ g2, const float* __restrict__ be2,
                        const float* __restrict__ tf, const double* __restrict__ st10,
                        const float* __restrict__ fg, const float* __restrict__ fbe,
                        const float* __restrict__ feat, float* __restrict__ out){
  __shared__ float l10[192], l12[192];
  if (threadIdx.x < 96){
    float2 a = bnstat(st10, threadIdx.x); l10[threadIdx.x*2]=a.x; l10[threadIdx.x*2+1]=a.y;
    float2 b = bnstat(st12, threadIdx.x); l12[threadIdx.x*2]=b.x; l12[threadIdx.x*2+1]=b.y;
  }
  __syncthreads();
  int idx = blockIdx.x*blockDim.x + threadIdx.x;
  int c = idx % CH;
  float fsd = fmaxf((tf[idx] - l10[c*2])*l10[c*2+1]*fg[c] + fbe[c], 0.f) + feat[idx];
  float v = (c2[idx] - l12[c*2])*l12[c*2+1]*g2[c] + be2[c];
  out[idx] = fmaxf(v + fsd, 0.f);
}

// ---------- launcher ----------
extern "C" void kernel_launch(void* const* d_in, const int* in_sizes, int n_in,
                              void* d_out, int out_size, void* d_ws, size_t ws_size,
                              hipStream_t stream)
{
  const float* x      = (const float*)d_in[0];
  const int*   ind    = (const int*)  d_in[1];
  const float* fp_w   = (const float*)d_in[2];
  const float* fp_b   = (const float*)d_in[3];
  const float* fp_g   = (const float*)d_in[4];
  const float* fp_be  = (const float*)d_in[5];
  const float* att_w1 = (const float*)d_in[6];
  const float* att_b1 = (const float*)d_in[7];
  const float* att_w2 = (const float*)d_in[8];
  const float* att_b2 = (const float*)d_in[9];
  const float* ff_w1  = (const float*)d_in[10];
  const float* ff_b1  = (const float*)d_in[11];
  const float* ff_g   = (const float*)d_in[12];
  const float* ff_be  = (const float*)d_in[13];
  const float* ff_w2  = (const float*)d_in[14];
  const float* ff_b2  = (const float*)d_in[15];
  const float* sa_w1  = (const float*)d_in[16];
  const float* sa_b1  = (const float*)d_in[17];
  const float* sa_w2  = (const float*)d_in[18];
  const float* sa_b2  = (const float*)d_in[19];
  const float* fj_w1  = (const float*)d_in[20];
  const float* fj_b1  = (const float*)d_in[21];
  const float* fj_g   = (const float*)d_in[22];
  const float* fj_be  = (const float*)d_in[23];
  const float* fj_w2  = (const float*)d_in[24];
  const float* fj_b2  = (const float*)d_in[25];
  const float* proj_w = (const float*)d_in[26];
  const float* proj_g = (const float*)d_in[27];
  const float* proj_be= (const float*)d_in[28];
  const float* lw_w   = (const float*)d_in[29];
  const float* lw_g   = (const float*)d_in[30];
  const float* lw_be  = (const float*)d_in[31];
  const float* w_w    = (const float*)d_in[32];
  const float* adp_w  = (const float*)d_in[33];
  const float* fuse_w = (const float*)d_in[34];
  const float* fuse_g = (const float*)d_in[35];
  const float* fuse_be= (const float*)d_in[36];
  const float* conv1_w= (const float*)d_in[37];
  const float* bn1_g  = (const float*)d_in[38];
  const float* bn1_be = (const float*)d_in[39];
  const float* conv2_w= (const float*)d_in[40];
  const float* bn2_g  = (const float*)d_in[41];
  const float* bn2_be = (const float*)d_in[42];
  float* outp = (float*)d_out;
  (void)in_sizes; (void)n_in; (void)out_size;

  char* ws = (char*)d_ws;
  size_t off = 0;
  auto alloc = [&](size_t bytes)->size_t{
    off = (off + 255) & ~(size_t)255;
    size_t o = off; off += bytes; return o;
  };
  const size_t FNC = (size_t)NCELEM*4;
  size_t o_packed = alloc((size_t)NPTS*4);
  size_t o_start  = alloc(32);
  size_t o_ball   = alloc((size_t)NBALL*4);
  size_t o_dens   = alloc((size_t)NPTS*4);
  size_t o_lin    = alloc((size_t)NPTS*4);
  size_t o_t9     = alloc((size_t)NPTS*9*4);
  size_t o_enh    = alloc((size_t)NPTS*9*4);
  size_t o_gm     = alloc((size_t)NPTS*4);
  size_t o_gsz    = alloc((size_t)NPTS*3*4);
  size_t o_reps   = alloc(16*4);
  size_t o_bkt    = alloc((size_t)3*100*3*4);
  size_t o_seg    = alloc((size_t)3*NPTS*4);
  size_t o_table  = alloc((size_t)65536*4);
  size_t o_nbr    = alloc((size_t)NPTS*27*4);
  size_t o_ptlist = alloc((size_t)27*NPTS*4);
  size_t o_t64    = alloc((size_t)NPTS*64*4);
  size_t o_htk    = alloc((size_t)3*HTSZ*8);
  size_t o_htv    = alloc((size_t)3*HTSZ*4);
  // --- contiguous zero region ---
  size_t o_S      = alloc(3*FNC);
  size_t o_E      = alloc(3*FNC);
  size_t o_F      = alloc(3*FNC);
  size_t o_stats  = alloc((size_t)13*192*8);   // (sum,sumsq) doubles, accumulated atomically
  size_t o_cnt    = alloc((size_t)3*NPTS*4);
  size_t o_rank   = alloc((size_t)NPTS*4);
  size_t o_tapcnt = alloc(32*4);
  size_t o_done   = alloc(16);
  size_t o_maxenc = alloc(16*4);
  size_t zend = off;
  // --- big slots ---
  size_t o_T96 = alloc(FNC);
  size_t o_fu  = alloc(FNC);
  size_t o_feat= alloc(FNC);
  size_t o_tlw = alloc(3*FNC);
  size_t o_pw2 = alloc(3*FNC);
  size_t o_tp  = alloc(4*FNC);
  size_t o_agg = alloc(FNC);
  size_t o_tf  = alloc(FNC);
  size_t o_fsd = alloc(FNC);
  size_t o_c1  = alloc(FNC);
  size_t o_f1  = alloc(FNC);
  size_t o_c2  = alloc(FNC);
  size_t o_part = alloc((size_t)NPTS*27*CH*4);
  bool use_part = (off <= ws_size);

  double* stats = (double*)(ws + o_stats);
  long zcount = (long)((zend - o_S)/4);

  k_setup0<<<dim3(2048), dim3(256), 0, stream>>>((int*)(ws+o_S), zcount,
      (unsigned long long*)(ws+o_htk), (int*)(ws+o_htv), (int*)(ws+o_table), (int*)(ws+o_start));
  k_setup1<<<dim3(25), 256, 0, stream>>>(ind, (unsigned*)(ws+o_packed),
      (int*)(ws+o_start), (int*)(ws+o_table), (unsigned*)(ws+o_ball));

  // stage A
  k_mm<<<dim3(192,1), 256, 0, stream>>>(x, fp_w, fp_b, (float*)(ws+o_t9), 96, 9,
      0,0,0,0, nullptr,0, nullptr,nullptr,0, nullptr,nullptr,nullptr, nullptr, 0, stats+0);
  k_p_att_enh<<<dim3(24), 256, 0, stream>>>((float*)(ws+o_t9), stats+0, fp_g, fp_be,
      att_w1, att_b1, att_w2, att_b2, (float*)(ws+o_enh));

  k_mm<<<dim3(192,1), 256, 0, stream>>>((float*)(ws+o_enh), ff_w1, ff_b1, (float*)(ws+o_T96), 9, 96,
      0,0,0,0, nullptr,0, nullptr,nullptr,0, nullptr,nullptr,nullptr, nullptr, 0, stats+1*192);
  k_mm<<<dim3(192,1), 256, 0, stream>>>((float*)(ws+o_T96), ff_w2, ff_b2, (float*)(ws+o_fu), 96, 96,
      0,0,0,0, stats+1*192,0, ff_g, ff_be,0, nullptr,nullptr,nullptr, nullptr, 1, nullptr);

  k_sem_feat<<<dim3(1536), 256, 0, stream>>>((float*)(ws+o_fu), x, sa_w1, sa_b1, sa_w2, sa_b2,
      (float*)(ws+o_feat));

  k_knn<<<dim3(1536), 256, 0, stream>>>((unsigned*)(ws+o_packed), (int*)(ws+o_table),
      (unsigned*)(ws+o_ball), (float*)(ws+o_dens), (float*)(ws+o_lin));

  k_mm<<<dim3(192,1), 256, 0, stream>>>((float*)(ws+o_feat), fj_w1, fj_b1, (float*)(ws+o_t64), 96, 64,
      0,0,0,0, nullptr,0, nullptr,nullptr,0, nullptr,nullptr,nullptr, nullptr, 0, stats+2*192);
  k_geo<<<dim3(24), 256, 0, stream>>>((float*)(ws+o_t64), stats+2*192, fj_g, fj_be, fj_w2, fj_b2,
      (float*)(ws+o_dens), (float*)(ws+o_lin), (float*)(ws+o_gsz), (float*)(ws+o_gm));

  k_rank<<<dim3(24,8), 256, 0, stream>>>((float*)(ws+o_gm), (int*)(ws+o_rank));
  k_scatter_reps<<<dim3(24), 256, 0, stream>>>((int*)(ws+o_rank), (float*)(ws+o_gsz),
      (float*)(ws+o_bkt), (int*)(ws+o_done), (float*)(ws+o_reps));

  k_seg_build<<<dim3(24,3), 256, 0, stream>>>(ind, (float*)(ws+o_reps), (int*)(ws+o_start),
      (unsigned long long*)(ws+o_htk), (int*)(ws+o_htv));
  k_seg_lookup<<<dim3(24,3), 256, 0, stream>>>(ind, (float*)(ws+o_reps), (int*)(ws+o_start),
      (unsigned long long*)(ws+o_htk), (int*)(ws+o_htv), (int*)(ws+o_seg), (int*)(ws+o_cnt));

  // branch pipelines (batched over 3)
  k_mm<<<dim3(192,3), 256, 0, stream>>>((float*)(ws+o_feat), lw_w, nullptr, (float*)(ws+o_tlw), 96, 96,
      0, 96*96, NCELEM, 0, nullptr,0, nullptr,nullptr,0, nullptr,nullptr,nullptr, nullptr, 0, stats+3*192);
  k_pw_accum<<<dim3(2304,3), 256, 0, stream>>>((float*)(ws+o_tlw), stats+3*192, lw_g, lw_be,
      (int*)(ws+o_seg), (float*)(ws+o_S));
  k_mm<<<dim3(192,3), 256, 0, stream>>>((float*)(ws+o_tlw), w_w, nullptr, (float*)(ws+o_pw2), 96, 96,
      NCELEM, 96*96, NCELEM, 0, stats+3*192,192, lw_g, lw_be,96,
      (float*)(ws+o_S), (int*)(ws+o_seg), (int*)(ws+o_cnt), (unsigned*)(ws+o_maxenc), 2, nullptr);
  k_exp_accum<<<dim3(2304,3), 256, 0, stream>>>((float*)(ws+o_pw2), (unsigned*)(ws+o_maxenc),
      (int*)(ws+o_seg), (float*)(ws+o_E));
  k_mm<<<dim3(192,4), 256, 0, stream>>>((float*)(ws+o_feat), proj_w, nullptr, (float*)(ws+o_tp), 96, 96,
      0, 96*96, NCELEM, 0, nullptr,0, nullptr,nullptr,0, nullptr,nullptr,nullptr, nullptr, 0, stats+6*192);
  k_pf_accum<<<dim3(2304,3), 256, 0, stream>>>((float*)(ws+o_tp), stats+6*192, proj_g, proj_be,
      (float*)(ws+o_pw2), (unsigned*)(ws+o_maxenc), (int*)(ws+o_seg), (float*)(ws+o_E), (float*)(ws+o_F));
  k_adp_agg<<<dim3(192), 256, 0, stream>>>((float*)(ws+o_feat), adp_w, (float*)(ws+o_F),
      (int*)(ws+o_seg), (float*)(ws+o_agg));

  // fuse gemm (+ tf stats fused)
  k_mm_fuse<<<dim3(192), 256, 0, stream>>>((float*)(ws+o_tp) + (size_t)3*NCELEM, stats+9*192,
      proj_g + 3*96, proj_be + 3*96, (float*)(ws+o_agg), fuse_w, (float*)(ws+o_tf), stats+10*192);

  // sparse conv tail
  k_nbrlist<<<dim3(24), 256, 0, stream>>>(ind, (int*)(ws+o_table), (int*)(ws+o_nbr),
      (int*)(ws+o_tapcnt), (int*)(ws+o_ptlist));
  if (use_part){
    k_conv_gemm<<<dim3(192,27), 256, 0, stream>>>((float*)(ws+o_tf), conv1_w,
        (int*)(ws+o_tapcnt), (int*)(ws+o_ptlist),
        stats+10*192, fuse_g, fuse_be, (float*)(ws+o_feat), 2, (float*)(ws+o_part));
    k_conv_sum<<<dim3(NPTS*24/256), 256, 0, stream>>>((int*)(ws+o_nbr), (float*)(ws+o_part),
        (float*)(ws+o_c1), stats+11*192);
    k_conv_gemm<<<dim3(192,27), 256, 0, stream>>>((float*)(ws+o_c1), conv2_w,
        (int*)(ws+o_tapcnt), (int*)(ws+o_ptlist),
        stats+11*192, bn1_g, bn1_be, nullptr, 1, (float*)(ws+o_part));
    k_conv_sum<<<dim3(NPTS*24/256), 256, 0, stream>>>((int*)(ws+o_nbr), (float*)(ws+o_part),
        (float*)(ws+o_c2), stats+12*192);
  } else {
    k_fused<<<dim3(2304), 256, 0, stream>>>((float*)(ws+o_tf), stats+10*192, fuse_g, fuse_be,
        (float*)(ws+o_feat), (float*)(ws+o_fsd));
    k_zero<<<dim3(2304), dim3(256), 0, stream>>>((int*)(ws+o_c1), NCELEM);
    k_conv_gemm_atomic<<<dim3(192,27), 256, 0, stream>>>((float*)(ws+o_fsd), conv1_w,
        (int*)(ws+o_tapcnt), (int*)(ws+o_ptlist), (float*)(ws+o_c1));
    k_stats<<<dim3(96,1), 256, 0, stream>>>((float*)(ws+o_c1), 0, 96, stats+11*192, 0);
    k_bnrelu<<<dim3(2304), 256, 0, stream>>>((float*)(ws+o_c1), stats+11*192, bn1_g, bn1_be,
        (float*)(ws+o_f1));
    k_zero<<<dim3(2304), dim3(256), 0, stream>>>((int*)(ws+o_c2), NCELEM);
    k_conv_gemm_atomic<<<dim3(192,27), 256, 0, stream>>>((float*)(ws+o_f1), conv2_w,
        (int*)(ws+o_tapcnt), (int*)(ws+o_ptlist), (float*)(ws+o_c2));
    k_stats<<<dim3(96,1), 256, 0, stream>>>((float*)(ws+o_c2), 0, 96, stats+12*192, 0);
  }
  k_final<<<dim3(2304), 256, 0, stream>>>((float*)(ws+o_c2), stats+12*192, bn2_g, bn2_be,
      (float*)(ws+o_tf), stats+10*192, fuse_g, fuse_be, (float*)(ws+o_feat), outp);
}

// Round 18
// 484.674 us; speedup vs baseline: 1.0660x; 1.0660x over previous
//
#include <hip/hip_runtime.h>
#include <cstdint>

#define NPTS 6144
#define CH 96
#define NCELEM (NPTS*CH)
#define HTSZ 16384
#define NBALL 514   // lattice points with 0 < d2 <= 25

// ---------- helpers ----------
__device__ __forceinline__ unsigned fenc(float f){
  unsigned u = __float_as_uint(f);
  return (u & 0x80000000u) ? ~u : (u | 0x80000000u);
}
__device__ __forceinline__ float fdec(unsigned u){
  unsigned b = (u & 0x80000000u) ? (u & 0x7FFFFFFFu) : ~u;
  return __uint_as_float(b);
}

__device__ void eig3(double a00,double a01,double a02,double a11,double a12,double a22,
                     double &e0,double &e1,double &e2){
  double p1 = a01*a01 + a02*a02 + a12*a12;
  double q = (a00+a11+a22)/3.0;
  double b00=a00-q, b11=a11-q, b22=a22-q;
  double p2 = b00*b00 + b11*b11 + b22*b22 + 2.0*p1;
  if (p2 <= 1e-300){ e0=e1=e2=q; return; }
  double pp = sqrt(p2/6.0);
  double inv = 1.0/pp;
  double c00=b00*inv, c01=a01*inv, c02=a02*inv, c11=b11*inv, c12=a12*inv, c22=b22*inv;
  double det = c00*(c11*c22-c12*c12) - c01*(c01*c22-c12*c02) + c02*(c01*c12-c11*c02);
  double r = det*0.5;
  r = r < -1.0 ? -1.0 : (r > 1.0 ? 1.0 : r);
  double phi = acos(r)/3.0;
  e0 = q + 2.0*pp*cos(phi);
  e2 = q + 2.0*pp*cos(phi + 2.0943951023931953);
  e1 = 3.0*q - e0 - e2;
}

// ---------- fused setup 0: all zero/const inits ----------
__global__ void k_setup0(int* __restrict__ zb, long zcount,
                         unsigned long long* __restrict__ htk, int* __restrict__ htv,
                         int* __restrict__ table, int* __restrict__ startmm){
  long i = (long)blockIdx.x*blockDim.x + threadIdx.x;
  long st = (long)gridDim.x*blockDim.x;
  for (long j=i; j<zcount; j+=st) zb[j] = 0;
  for (long j=i; j<3*HTSZ; j+=st){ htk[j] = ~0ull; htv[j] = 0x7fffffff; }
  for (long j=i; j<2*32768; j+=st) table[j] = -1;
  if (i < 3) startmm[i] = 0x7fffffff;
  else if (i < 6) startmm[i] = 0;
}
// ---------- fused setup 1: pack + coord min/max + table fill | ball ----------
__global__ void __launch_bounds__(256) k_setup1(const int* __restrict__ ind,
                                                unsigned* __restrict__ packed,
                                                int* __restrict__ startmm,
                                                int* __restrict__ table,
                                                unsigned* __restrict__ ball){
  __shared__ int mn[3], mx[3];
  __shared__ int hcnt[32], hbase[32], hpos[32];
  int tid = threadIdx.x;
  if (blockIdx.x < 24){
    if (tid < 3){ mn[tid] = 0x7fffffff; mx[tid] = 0; }
    __syncthreads();
    int p = blockIdx.x*256 + tid;
    int b = ind[p*4], z = ind[p*4+1], y = ind[p*4+2], x = ind[p*4+3];
    packed[p] = (unsigned)((b<<15)|(z<<10)|(y<<5)|x);
    table[((b*32+z)*32+y)*32+x] = p;
    atomicMin(&mn[0], z); atomicMin(&mn[1], y); atomicMin(&mn[2], x);
    atomicMax(&mx[0], z); atomicMax(&mx[1], y); atomicMax(&mx[2], x);
    __syncthreads();
    if (tid < 3){
      atomicMin(&startmm[tid], mn[tid]);
      atomicMax(&startmm[3+tid], mx[tid]);
    }
  } else {
    if (tid < 32){ hcnt[tid] = 0; hpos[tid] = 0; }
    __syncthreads();
    for (int i=tid; i<1331; i+=256){
      int dz = i/121, rm = i - dz*121, dy = rm/11, dx = rm - dy*11;
      int a = dz-5, b = dy-5, c = dx-5;
      int d2 = a*a + b*b + c*c;
      if (d2 > 0 && d2 <= 25) atomicAdd(&hcnt[d2], 1);
    }
    __syncthreads();
    if (tid == 0){
      int acc = 0;
      for (int d=1; d<=25; ++d){ hbase[d] = acc; acc += hcnt[d]; }
    }
    __syncthreads();
    for (int i=tid; i<1331; i+=256){
      int dz = i/121, rm = i - dz*121, dy = rm/11, dx = rm - dy*11;
      int a = dz-5, b = dy-5, c = dx-5;
      int d2 = a*a + b*b + c*c;
      if (d2 > 0 && d2 <= 25){
        int pos = hbase[d2] + atomicAdd(&hpos[d2], 1);
        ball[pos] = ((unsigned)d2<<16)|((unsigned)dz<<10)|((unsigned)dy<<5)|(unsigned)dx;
      }
    }
  }
}

// ---------- generic GEMM: O = act(A)@W.T + bias (k-major LDS) ----------
__global__ void __launch_bounds__(256) k_mm(
    const float* __restrict__ Abase, const float* __restrict__ Wbase,
    const float* __restrict__ biasBase, float* __restrict__ Obase,
    int CIN, int COUT,
    long sA, long sW, long sO, long sBias,
    const float* __restrict__ statsBase, long sStats,
    const float* __restrict__ gBase, const float* __restrict__ beBase, long sGB,
    const float* __restrict__ SsumBase, const int* __restrict__ segBase, const int* __restrict__ cntBase,
    unsigned* maxenc, int mode)
{
  int zb = blockIdx.y;
  const float* A = Abase + (long)zb*sA;
  const float* W = Wbase + (long)zb*sW;
  float* O = Obase + (long)zb*sO;
  const float* st = statsBase ? statsBase + (long)zb*sStats : nullptr;
  const float* g  = gBase ? gBase + (long)zb*sGB : nullptr;
  const float* be = beBase ? beBase + (long)zb*sGB : nullptr;
  const float* Ss = SsumBase ? SsumBase + (long)zb*NCELEM : nullptr;
  const int* seg  = segBase ? segBase + (long)zb*NPTS : nullptr;
  const int* cnt  = cntBase ? cntBase + (long)zb*NPTS : nullptr;

  __shared__ float Alt[96*34];
  __shared__ float Wlt[96*98];
  int tid = threadIdx.x;
  int r0 = blockIdx.x*32;
  for (int idx = tid; idx < CIN*COUT; idx += 256){
    int co = idx / CIN, k = idx - co*CIN;
    Wlt[k*98 + co] = W[idx];
  }
  for (int idx = tid; idx < 32*CIN; idx += 256){
    int ir = idx / CIN, k = idx - ir*CIN;
    int row = r0 + ir;
    float v = A[(long)row*CIN + k];
    if (mode >= 1) v = fmaxf((v - st[k*2])*st[k*2+1]*g[k] + be[k], 0.f);
    if (mode == 2){
      int s = seg[row];
      float cf = fmaxf((float)cnt[s], 1.f);
      v -= Ss[(long)s*CH + k] / cf;
    }
    Alt[k*34 + ir] = v;
  }
  __syncthreads();
  float lmax = -3.4e38f;
  if (COUT == 96){
    int rp = tid >> 4, cg = tid & 15;
    int co0 = cg*6;
    float acc0[6], acc1[6];
    #pragma unroll
    for (int j=0;j<6;++j){
      float b = biasBase ? biasBase[(long)zb*sBias + co0 + j] : 0.f;
      acc0[j] = b; acc1[j] = b;
    }
    int ra = 2*rp;
    for (int k=0;k<CIN;++k){
      float2 a  = *(const float2*)&Alt[k*34 + ra];
      float2 w0 = *(const float2*)&Wlt[k*98 + co0];
      float2 w1 = *(const float2*)&Wlt[k*98 + co0 + 2];
      float2 w2 = *(const float2*)&Wlt[k*98 + co0 + 4];
      acc0[0] = fmaf(a.x, w0.x, acc0[0]); acc1[0] = fmaf(a.y, w0.x, acc1[0]);
      acc0[1] = fmaf(a.x, w0.y, acc0[1]); acc1[1] = fmaf(a.y, w0.y, acc1[1]);
      acc0[2] = fmaf(a.x, w1.x, acc0[2]); acc1[2] = fmaf(a.y, w1.x, acc1[2]);
      acc0[3] = fmaf(a.x, w1.y, acc0[3]); acc1[3] = fmaf(a.y, w1.y, acc1[3]);
      acc0[4] = fmaf(a.x, w2.x, acc0[4]); acc1[4] = fmaf(a.y, w2.x, acc1[4]);
      acc0[5] = fmaf(a.x, w2.y, acc0[5]); acc1[5] = fmaf(a.y, w2.y, acc1[5]);
    }
    int rb = ra+1;
    #pragma unroll
    for (int j=0;j<6;++j){
      O[(long)(r0+ra)*96 + co0 + j] = acc0[j];
      O[(long)(r0+rb)*96 + co0 + j] = acc1[j];
      lmax = fmaxf(lmax, fmaxf(acc0[j], acc1[j]));
    }
  } else {
    for (int idx = tid; idx < 32*COUT; idx += 256){
      int ir = idx/COUT, co = idx - ir*COUT;
      float acc = biasBase ? biasBase[(long)zb*sBias + co] : 0.f;
      for (int k=0;k<CIN;++k) acc = fmaf(Alt[k*34+ir], Wlt[k*98+co], acc);
      O[(long)(r0+ir)*COUT + co] = acc;
      lmax = fmaxf(lmax, acc);
    }
  }
  if (maxenc){
    __shared__ float rmx[256];
    rmx[tid] = lmax; __syncthreads();
    for (int s2=128; s2>0; s2>>=1){
      if (tid < s2) rmx[tid] = fmaxf(rmx[tid], rmx[tid+s2]);
      __syncthreads();
    }
    if (tid == 0) atomicMax(&maxenc[zb], fenc(rmx[0]));
  }
}

// fused gemm: tf = [relu(bn(tp3)), agg] @ fuse_w.T   (CIN=192, COUT=96)
__global__ void __launch_bounds__(256) k_mm_fuse(
    const float* __restrict__ tp3, const float* __restrict__ st,
    const float* __restrict__ pg3, const float* __restrict__ pbe3,
    const float* __restrict__ agg, const float* __restrict__ fw, float* __restrict__ tf)
{
  __shared__ float Alt[192*34];
  __shared__ float Wlt[96*98];
  int tid = threadIdx.x, r0 = blockIdx.x*32;
  for (int idx = tid; idx < 32*192; idx += 256){
    int ir = idx/192, k = idx - ir*192;
    int row = r0 + ir;
    float v;
    if (k < 96){
      v = tp3[(long)row*96 + k];
      v = fmaxf((v - st[k*2])*st[k*2+1]*pg3[k] + pbe3[k], 0.f);
    } else {
      v = agg[(long)row*96 + (k-96)];
    }
    Alt[k*34 + ir] = v;
  }
  int rp = tid >> 4, cg = tid & 15, co0 = cg*6;
  float acc0[6] = {0,0,0,0,0,0}, acc1[6] = {0,0,0,0,0,0};
  int ra = 2*rp, rb = ra+1;
  for (int h=0; h<2; ++h){
    __syncthreads();
    for (int idx = tid; idx < 96*96; idx += 256){
      int co = idx/96, k = idx - co*96;
      Wlt[k*98+co] = fw[(long)co*192 + h*96 + k];
    }
    __syncthreads();
    for (int k=0;k<96;++k){
      float2 a  = *(const float2*)&Alt[(h*96 + k)*34 + ra];
      float2 w0 = *(const float2*)&Wlt[k*98 + co0];
      float2 w1 = *(const float2*)&Wlt[k*98 + co0 + 2];
      float2 w2 = *(const float2*)&Wlt[k*98 + co0 + 4];
      acc0[0] = fmaf(a.x, w0.x, acc0[0]); acc1[0] = fmaf(a.y, w0.x, acc1[0]);
      acc0[1] = fmaf(a.x, w0.y, acc0[1]); acc1[1] = fmaf(a.y, w0.y, acc1[1]);
      acc0[2] = fmaf(a.x, w1.x, acc0[2]); acc1[2] = fmaf(a.y, w1.x, acc1[2]);
      acc0[3] = fmaf(a.x, w1.y, acc0[3]); acc1[3] = fmaf(a.y, w1.y, acc1[3]);
      acc0[4] = fmaf(a.x, w2.x, acc0[4]); acc1[4] = fmaf(a.y, w2.x, acc1[4]);
      acc0[5] = fmaf(a.x, w2.y, acc0[5]); acc1[5] = fmaf(a.y, w2.y, acc1[5]);
    }
  }
  #pragma unroll
  for (int j=0;j<6;++j){
    tf[(long)(r0+ra)*96 + co0 + j] = acc0[j];
    tf[(long)(r0+rb)*96 + co0 + j] = acc1[j];
  }
}

// ---------- column stats (mean, 1/sqrt(var+eps)) over N rows ----------
__global__ void k_stats(const float* __restrict__ Abase, long sA, int COLS,
                        float* __restrict__ statsBase, long sStats){
  int col = blockIdx.x, zb = blockIdx.y;
  const float* A = Abase + (long)zb*sA;
  double s = 0.0, q = 0.0;
  for (int r = threadIdx.x; r < NPTS; r += 256){
    double v = (double)A[(long)r*COLS + col];
    s += v; q += v*v;
  }
  __shared__ double ls[256], lq[256];
  ls[threadIdx.x] = s; lq[threadIdx.x] = q; __syncthreads();
  for (int t=128; t>0; t>>=1){
    if (threadIdx.x < t){ ls[threadIdx.x] += ls[threadIdx.x+t]; lq[threadIdx.x] += lq[threadIdx.x+t]; }
    __syncthreads();
  }
  if (threadIdx.x == 0){
    double mean = ls[0]/NPTS;
    double var = lq[0]/NPTS - mean*mean;
    float* stp = statsBase + (long)zb*sStats + col*2;
    stp[0] = (float)mean;
    stp[1] = (float)(1.0/sqrt(var + 1e-5));
  }
}

// ---------- stage A: p = relu(bn(t9)); attention; enh ----------
__global__ void k_p_att_enh(const float* __restrict__ t9, const float* __restrict__ st,
                            const float* __restrict__ fg, const float* __restrict__ fbe,
                            const float* __restrict__ aw1, const float* __restrict__ ab1,
                            const float* __restrict__ aw2, const float* __restrict__ ab2,
                            float* __restrict__ enh){
  int p = blockIdx.x*blockDim.x + threadIdx.x;
  if (p >= NPTS) return;
  float pp[9];
  #pragma unroll
  for (int c=0;c<9;++c){
    float v = t9[p*9+c];
    pp[c] = fmaxf((v - st[c*2])*st[c*2+1]*fg[c] + fbe[c], 0.f);
  }
  float eo[9];
  eo[0]=pp[0]; eo[1]=pp[1]; eo[2]=pp[2];
  #pragma unroll
  for (int i=0;i<2;++i){
    const float* w1 = aw1 + i*48;
    const float* b1 = ab1 + i*16;
    const float* w2 = aw2 + i*48;
    const float* b2 = ab2 + i*3;
    const float* f = pp + 3 + i*3;
    float h[16];
    #pragma unroll
    for (int j=0;j<16;++j){
      float s = b1[j];
      #pragma unroll
      for (int k=0;k<3;++k) s = fmaf(f[k], w1[j*3+k], s);
      h[j] = fmaxf(s, 0.f);
    }
    #pragma unroll
    for (int o=0;o<3;++o){
      float s = b2[o];
      #pragma unroll
      for (int j=0;j<16;++j) s = fmaf(h[j], w2[o*16+j], s);
      float a = 1.f/(1.f + expf(-s));
      eo[3+i*3+o] = f[o]*a;
    }
  }
  #pragma unroll
  for (int c=0;c<9;++c) enh[p*9+c] = eo[c];
}

// ---------- sem attention + feat blend (wave per point) ----------
__global__ void __launch_bounds__(256) k_sem_feat(
    const float* __restrict__ fu, const float* __restrict__ x,
    const float* __restrict__ w1, const float* __restrict__ b1,
    const float* __restrict__ w2, const float* __restrict__ b2,
    float* __restrict__ feat){
  int wid = (blockIdx.x*blockDim.x + threadIdx.x) >> 6;
  int lane = threadIdx.x & 63;
  if (wid >= NPTS) return;
  const float* fr = fu + (long)wid*96;
  float partial = 0.f;
  if (lane < 48){
    float h = b1[lane];
    for (int k=0;k<96;++k) h = fmaf(fr[k], w1[lane*96+k], h);
    h = fmaxf(h, 0.f);
    partial = h * w2[lane];
  }
  for (int m=32; m; m>>=1) partial += __shfl_xor(partial, m);
  float sem = 1.f/(1.f + expf(-(partial + b2[0])));
  for (int c=lane; c<96; c+=64){
    float f = fr[c];
    feat[(long)wid*96+c] = f*sem + x[(long)wid*96+c]*(1.f - sem);
  }
}

// ---------- exact KNN + covariance eigen (wave per point) ----------
// Round-14 version: u32 keys, LDS pk staging, sorted ball + early exit.
__global__ void __launch_bounds__(256) k_knn(const unsigned* __restrict__ packed,
                                             const int* __restrict__ table,
                                             const unsigned* __restrict__ ball,
                                             float* __restrict__ density, float* __restrict__ linearity){
  __shared__ unsigned pk[NPTS];
  for (int i=threadIdx.x; i<NPTS; i+=256) pk[i] = packed[i];
  __syncthreads();
  int pid = blockIdx.x*4 + (threadIdx.x>>6);
  int lane = threadIdx.x & 63;
  unsigned mypc = pk[pid];
  int myb = (int)(mypc>>15);
  int mz = (int)((mypc>>10)&31), my_=(int)((mypc>>5)&31), mx_=(int)(mypc&31);
  unsigned s[16];
  #pragma unroll
  for (int t=0;t<16;++t) s[t] = 0xFFFFFFFFu;
  int cnt = 0;
  const int tbase = myb*32768;
  for (int it=0; it<9; ++it){
    int i = lane + it*64;
    if (i < NBALL){
      unsigned e = ball[i];
      int d2 = (int)(e >> 16);
      int dz = (int)((e>>10)&31) - 5;
      int dy = (int)((e>>5)&31) - 5;
      int dx = (int)(e&31) - 5;
      int zz = mz+dz, yy = my_+dy, xx = mx_+dx;
      if ((unsigned)zz < 32u && (unsigned)yy < 32u && (unsigned)xx < 32u){
        int j = table[tbase + (zz*32+yy)*32+xx];
        if (j >= 0){
          ++cnt;
          unsigned key = ((unsigned)d2<<13) | (unsigned)j;
          if (key < s[15]){
            s[15] = key;
            #pragma unroll
            for (int t=15;t>0;--t){
              unsigned a = s[t-1], b = s[t];
              unsigned lo = a<b?a:b, hi = a<b?b:a;
              s[t-1]=lo; s[t]=hi;
            }
          }
        }
      }
    }
    int nxt = (it+1)*64;
    if (nxt >= NBALL) break;
    int tot = cnt;
    for (int m=32; m; m>>=1) tot += __shfl_xor(tot, m);
    unsigned dlast = ball[nxt-1] >> 16;
    unsigned dnext = ball[nxt] >> 16;
    if (tot >= 16 && dnext > dlast) break;
  }
  int tot = cnt;
  for (int m=32; m; m>>=1) tot += __shfl_xor(tot, m);
  if (tot < 16){
    #pragma unroll
    for (int t=0;t<16;++t) s[t] = 0xFFFFFFFFu;
    for (int it=0; it<96; ++it){
      int j = lane + it*64;
      unsigned pc = pk[j];
      if (j != pid && (int)(pc>>15) == myb){
        int dz = (int)((pc>>10)&31) - mz;
        int dy = (int)((pc>>5)&31) - my_;
        int dx = (int)(pc&31) - mx_;
        unsigned d2 = (unsigned)(dz*dz + dy*dy + dx*dx);
        unsigned key = (d2<<13) | (unsigned)j;
        if (key < s[15]){
          s[15] = key;
          #pragma unroll
          for (int t=15;t>0;--t){
            unsigned a = s[t-1], b = s[t];
            unsigned lo = a<b?a:b, hi = a<b?b:a;
            s[t-1]=lo; s[t]=hi;
          }
        }
      }
    }
  }
  float sdist = 0.f;
  int sz=0,sy=0,sx=0,szz=0,syy=0,sxx=0,szy=0,szx=0,syx=0;
  for (int r=0;r<16;++r){
    unsigned m = s[0];
    #pragma unroll
    for (int w=32; w; w>>=1){
      unsigned o = (unsigned)__shfl_xor((int)m, w);
      m = m<o ? m : o;
    }
    bool own = (s[0] == m);
    #pragma unroll
    for (int t=0;t<15;++t) s[t] = own ? s[t+1] : s[t];
    if (own) s[15] = 0xFFFFFFFFu;
    unsigned idx = m & 8191u;
    unsigned d2 = m >> 13;
    sdist += sqrtf((float)d2);
    unsigned pc = pk[idx];
    int nz=(int)((pc>>10)&31), ny=(int)((pc>>5)&31), nx=(int)(pc&31);
    sz+=nz; sy+=ny; sx+=nx;
    szz+=nz*nz; syy+=ny*ny; sxx+=nx*nx; szy+=nz*ny; szx+=nz*nx; syx+=ny*nx;
  }
  if (lane == 0){
    double m0 = sz/16.0, m1 = sy/16.0, m2 = sx/16.0;
    float c00 = (float)(((double)szz - 16.0*m0*m0)/15.0);
    float c11 = (float)(((double)syy - 16.0*m1*m1)/15.0);
    float c22 = (float)(((double)sxx - 16.0*m2*m2)/15.0);
    float c01 = (float)(((double)szy - 16.0*m0*m1)/15.0);
    float c02 = (float)(((double)szx - 16.0*m0*m2)/15.0);
    float c12 = (float)(((double)syx - 16.0*m1*m2)/15.0);
    double e0,e1,e2;
    eig3((double)c00,(double)c01,(double)c02,(double)c11,(double)c12,(double)c22, e0,e1,e2);
    float s0 = (float)fabs(e0), s1 = (float)fabs(e1), s2 = (float)fabs(e2);
    float den = s0 + s1 + s2 + 1e-6f;
    float sn0 = s0/den, sn1 = s1/den, sn2 = s2/den;
    linearity[pid] = sn0 - (sn1 + sn2);
    float md = sdist * (1.f/16.f);
    density[pid] = 1.f/(md + 1e-6f);
  }
}

// ---------- geometry head ----------
__global__ void k_geo(const float* __restrict__ t64, const float* __restrict__ st,
                      const float* __restrict__ fg, const float* __restrict__ fbe,
                      const float* __restrict__ w2, const float* __restrict__ b2,
                      const float* __restrict__ density, const float* __restrict__ linearity,
                      float* __restrict__ gsz, float* __restrict__ gm){
  int p = blockIdx.x*blockDim.x + threadIdx.x;
  if (p >= NPTS) return;
  float fl[3];
  #pragma unroll
  for (int o=0;o<3;++o) fl[o] = b2[o];
  for (int k=0;k<64;++k){
    float v = t64[(long)p*64+k];
    v = fmaxf((v - st[k*2])*st[k*2+1]*fg[k] + fbe[k], 0.f);
    #pragma unroll
    for (int o=0;o<3;++o) fl[o] = fmaf(v, w2[o*64+k], fl[o]);
  }
  float mx = fmaxf(fl[0], fmaxf(fl[1], fl[2]));
  float e0 = expf(fl[0]-mx), e1 = expf(fl[1]-mx), e2 = expf(fl[2]-mx);
  float es = e0+e1+e2;
  float p0 = e0/es, p1 = e1/es, p2 = e2/es;
  float den = density[p], lin = linearity[p];
  float tw = (den*2.f + p0)/3.f;
  float bg = (fmaxf(1.f-lin, 1.f-den) + p1)/3.f;
  float ln = (lin*2.f + p2)/3.f;
  float g0 = tw*0.1f + bg*0.4f + ln*0.2f + 1e-6f;
  float g1 = tw*0.1f + bg*0.4f + ln*0.2f + 1e-6f;
  float g2 = tw*0.1f + bg*0.4f + ln*1.0f + 1e-6f;
  gsz[p*3+0]=g0; gsz[p*3+1]=g1; gsz[p*3+2]=g2;
  gm[p] = (g0+g1+g2)/3.f;
}

// ---------- rank-by-counting ----------
#define RNKCHUNK 768
__global__ void __launch_bounds__(256) k_rank(const float* __restrict__ gm, int* __restrict__ rank){
  __shared__ unsigned long long lk[RNKCHUNK];
  int j0 = blockIdx.y*RNKCHUNK;
  for (int i=threadIdx.x; i<RNKCHUNK; i+=256){
    int j = j0 + i;
    lk[i] = (((unsigned long long)fenc(gm[j]))<<13) | (unsigned long long)j;
  }
  __syncthreads();
  int p = blockIdx.x*256 + threadIdx.x;
  unsigned long long myk = (((unsigned long long)fenc(gm[p]))<<13) | (unsigned long long)p;
  int cnt = 0;
  #pragma unroll 4
  for (int i=0; i<RNKCHUNK; ++i) cnt += (lk[i] < myk) ? 1 : 0;
  atomicAdd(&rank[p], cnt);
}
// scatter + last-block reps (fused)
__global__ void __launch_bounds__(256) k_scatter_reps(const int* __restrict__ rank,
                                                      const float* __restrict__ gsz,
                                                      float* __restrict__ bkt,
                                                      int* __restrict__ done,
                                                      float* __restrict__ reps){
  __shared__ int lastf;
  int p = blockIdx.x*256 + threadIdx.x;
  int r = rank[p];
  int zb = -1, t = 0;
  if (r < 100){ zb = 2; t = r; }
  else if (r < 200){ zb = 0; t = r - 100; }
  else if (r >= NPTS-100){ zb = 1; t = r - (NPTS-100); }
  if (zb >= 0){
    #pragma unroll
    for (int d=0; d<3; ++d) bkt[(zb*100 + t)*3 + d] = gsz[p*3+d];
  }
  __threadfence();
  __syncthreads();
  if (threadIdx.x == 0) lastf = (atomicAdd(done, 1) == 23) ? 1 : 0;
  __syncthreads();
  if (lastf){
    __threadfence();
    int i = threadIdx.x;
    if (i < 9){
      int z = i/3, d = i - z*3;
      double s = 0.0;
      for (int tt=0; tt<100; ++tt) s += (double)bkt[(z*100 + tt)*3 + d];
      reps[i] = (float)(s/100.0);
    }
  }
}

// ---------- cluster id (inlined into seg_build/seg_lookup) ----------
__device__ __forceinline__ unsigned long long cluster_id(
    const int* __restrict__ ind, const float* __restrict__ reps,
    const int* __restrict__ startmm, int z, int p){
  long long mxp[3]; int cc[3];
  #pragma unroll
  for (int d=0; d<3; ++d){
    float sizev = fmaxf(reps[z*3+d], 1e-6f);
    float cf = floorf(((float)ind[p*4+1+d] - (float)startmm[d]) / sizev);
    int ci = (int)cf;
    ci = ci < 0 ? 0 : (ci > 4095 ? 4095 : ci);
    cc[d] = ci;
    float cfm = floorf(((float)startmm[3+d] - (float)startmm[d]) / sizev);
    int cm = (int)cfm;
    cm = cm < 0 ? 0 : (cm > 4095 ? 4095 : cm);
    mxp[d] = (long long)cm + 1;
  }
  long long b = ind[p*4];
  return (unsigned long long)(((b*mxp[0] + cc[0])*mxp[1] + cc[1])*mxp[2] + cc[2]);
}

// ---------- segment labels via hash table ----------
__device__ __forceinline__ int ht_hash(unsigned long long id){
  unsigned long long h = id * 0x9E3779B97F4A7C15ull;
  return (int)(h >> 49) & (HTSZ-1);
}
__global__ void k_seg_build(const int* __restrict__ ind, const float* __restrict__ reps,
                            const int* __restrict__ startmm,
                            unsigned long long* __restrict__ keys, int* __restrict__ vals){
  int z = blockIdx.y;
  int p = blockIdx.x*blockDim.x + threadIdx.x;
  if (p >= NPTS) return;
  unsigned long long id = cluster_id(ind, reps, startmm, z, p);
  unsigned long long* K = keys + (long)z*HTSZ;
  int* V = vals + (long)z*HTSZ;
  int slot = ht_hash(id);
  while (true){
    unsigned long long prev = atomicCAS(&K[slot], ~0ull, id);
    if (prev == ~0ull || prev == id){ atomicMin(&V[slot], p); break; }
    slot = (slot + 1) & (HTSZ-1);
  }
}
__global__ void k_seg_lookup(const int* __restrict__ ind, const float* __restrict__ reps,
                             const int* __restrict__ startmm,
                             const unsigned long long* __restrict__ keys, const int* __restrict__ vals,
                             int* __restrict__ seg, int* __restrict__ cnt){
  int z = blockIdx.y;
  int p = blockIdx.x*blockDim.x + threadIdx.x;
  if (p >= NPTS) return;
  unsigned long long id = cluster_id(ind, reps, startmm, z, p);
  const unsigned long long* K = keys + (long)z*HTSZ;
  int slot = ht_hash(id);
  while (K[slot] != id) slot = (slot + 1) & (HTSZ-1);
  int rep = vals[(long)z*HTSZ + slot];
  seg[(long)z*NPTS + p] = rep;
  atomicAdd(&cnt[(long)z*NPTS + rep], 1);
}

// ---------- branch segment ops ----------
__global__ void k_pw_accum(const float* __restrict__ tlw, const float* __restrict__ stats,
                           const float* __restrict__ g, const float* __restrict__ be,
                           const int* __restrict__ seg, float* __restrict__ S){
  int z = blockIdx.y;
  int idx = blockIdx.x*blockDim.x + threadIdx.x;
  int p = idx/CH, c = idx - p*CH;
  const float* st = stats + z*192;
  float v = tlw[(long)z*NCELEM + idx];
  v = fmaxf((v - st[c*2])*st[c*2+1]*g[z*CH+c] + be[z*CH+c], 0.f);
  atomicAdd(&S[(long)z*NCELEM + (long)seg[(long)z*NPTS+p]*CH + c], v);
}
__global__ void k_exp_accum(const float* __restrict__ pw2, const unsigned* __restrict__ maxenc,
                            const int* __restrict__ seg, float* __restrict__ E){
  int z = blockIdx.y;
  int idx = blockIdx.x*blockDim.x + threadIdx.x;
  int p = idx/CH, c = idx - p*CH;
  float mv = fdec(maxenc[z]);
  float v = expf(pw2[(long)z*NCELEM + idx] - mv);
  atomicAdd(&E[(long)z*NCELEM + (long)seg[(long)z*NPTS+p]*CH + c], v);
}
__global__ void k_pf_accum(const float* __restrict__ tp, const float* __restrict__ stats,
                           const float* __restrict__ pg, const float* __restrict__ pbe,
                           const float* __restrict__ pw2, const unsigned* __restrict__ maxenc,
                           const int* __restrict__ seg, const float* __restrict__ E,
                           float* __restrict__ F){
  int z = blockIdx.y;
  int idx = blockIdx.x*blockDim.x + threadIdx.x;
  int p = idx/CH, c = idx - p*CH;
  const float* st = stats + z*192;
  float v = tp[(long)z*NCELEM + idx];
  v = fmaxf((v - st[c*2])*st[c*2+1]*pg[z*CH+c] + pbe[z*CH+c], 0.f);
  float mv = fdec(maxenc[z]);
  int sg = seg[(long)z*NPTS+p];
  float w = expf(pw2[(long)z*NCELEM + idx] - mv) / (E[(long)z*NCELEM + (long)sg*CH + c] + 1e-6f);
  atomicAdd(&F[(long)z*NCELEM + (long)sg*CH + c], v*w);
}
// adp softmax + agg gather (fused)
__global__ void __launch_bounds__(256) k_adp_agg(
    const float* __restrict__ feat, const float* __restrict__ aw,
    const float* __restrict__ F, const int* __restrict__ seg,
    float* __restrict__ agg){
  __shared__ float ladp[32][3];
  __shared__ int lseg[32][3];
  int tid = threadIdx.x;
  int p0 = blockIdx.x*32;
  if (tid < 96){
    int pl = tid/3, z = tid - pl*3;
    const float* fr = feat + (long)(p0+pl)*CH;
    float a = 0.f;
    for (int k=0;k<CH;++k) a = fmaf(fr[k], aw[z*CH+k], a);
    ladp[pl][z] = a;
    lseg[pl][z] = seg[(long)z*NPTS + (p0+pl)];
  }
  __syncthreads();
  if (tid < 32){
    float a0 = ladp[tid][0], a1 = ladp[tid][1], a2 = ladp[tid][2];
    float m = fmaxf(a0, fmaxf(a1,a2));
    float e0 = expf(a0-m), e1 = expf(a1-m), e2 = expf(a2-m);
    float s = e0+e1+e2;
    ladp[tid][0]=e0/s; ladp[tid][1]=e1/s; ladp[tid][2]=e2/s;
  }
  __syncthreads();
  for (int e = tid; e < 32*CH; e += 256){
    int pl = e/CH, c = e - pl*CH;
    float s = 0.f;
    #pragma unroll
    for (int z=0;z<3;++z)
      s = fmaf(ladp[pl][z], F[(long)z*NCELEM + (long)lseg[pl][z]*CH + c], s);
    agg[(long)p0*CH + e] = s;
  }
}

// ---------- fallback elementwise (unfused path only) ----------
__global__ void k_zero(int* p, long n){
  long i = (long)blockIdx.x*blockDim.x + threadIdx.x;
  long st = (long)gridDim.x*blockDim.x;
  for (; i < n; i += st) p[i] = 0;
}
__global__ void k_fused(const float* __restrict__ tf, const float* __restrict__ st,
                        const float* __restrict__ fg, const float* __restrict__ fbe,
                        const float* __restrict__ feat, float* __restrict__ fused){
  int idx = blockIdx.x*blockDim.x + threadIdx.x;
  int c = idx % CH;
  float v = tf[idx];
  v = fmaxf((v - st[c*2])*st[c*2+1]*fg[c] + fbe[c], 0.f);
  fused[idx] = v + feat[idx];
}
__global__ void k_bnrelu(const float* __restrict__ a, const float* __restrict__ st,
                         const float* __restrict__ g, const float* __restrict__ be,
                         float* __restrict__ o){
  int idx = blockIdx.x*blockDim.x + threadIdx.x;
  int c = idx % CH;
  float v = a[idx];
  o[idx] = fmaxf((v - st[c*2])*st[c*2+1]*g[c] + be[c], 0.f);
}

// ---------- conv tail ----------
__global__ void __launch_bounds__(256) k_nbrlist(const int* __restrict__ ind,
                                                 const int* __restrict__ table,
                                                 int* __restrict__ nbrtab,
                                                 int* __restrict__ tapcnt,
                                                 int* __restrict__ ptlist){
  __shared__ int pb[256], pz[256], py[256], px[256];
  __shared__ int lcnt[27], lbase[27], lpos[27];
  int tid = threadIdx.x;
  if (tid < 27){ lcnt[tid] = 0; lpos[tid] = 0; }
  int p0 = blockIdx.x*256;
  pb[tid] = ind[(p0+tid)*4];
  pz[tid] = ind[(p0+tid)*4+1];
  py[tid] = ind[(p0+tid)*4+2];
  px[tid] = ind[(p0+tid)*4+3];
  __syncthreads();
  int base = blockIdx.x*6912;
  int qv[27];
  #pragma unroll 1
  for (int j = 0; j < 27; ++j){
    int i = tid + j*256;
    int pl = i/27, tap = i - pl*27;
    int dz = tap/9 - 1;
    int rm = tap % 9;
    int dy = rm/3 - 1, dx = rm%3 - 1;
    int z = pz[pl]+dz, y = py[pl]+dy, x = px[pl]+dx;
    int q = -1;
    if ((unsigned)z < 32u && (unsigned)y < 32u && (unsigned)x < 32u)
      q = table[((pb[pl]*32+z)*32+y)*32+x];
    qv[j] = q;
    nbrtab[base + i] = q;
    if (q >= 0) atomicAdd(&lcnt[tap], 1);
  }
  __syncthreads();
  if (tid < 27) lbase[tid] = atomicAdd(&tapcnt[tid], lcnt[tid]);
  __syncthreads();
  #pragma unroll 1
  for (int j = 0; j < 27; ++j){
    int q = qv[j];
    if (q >= 0){
      int i = tid + j*256;
      int tap = i % 27;
      int p = p0 + i/27;
      int pos = lbase[tap] + atomicAdd(&lpos[tap], 1);
      ptlist[tap*NPTS + pos] = (p<<16) | q;
    }
  }
}
// per-tap gather-GEMM with optional fused BN(+res) on staging; plain stores
__global__ void __launch_bounds__(256) k_conv_gemm(
    const float* __restrict__ src, const float* __restrict__ Wc,
    const int* __restrict__ tapcnt, const int* __restrict__ ptlist,
    const float* __restrict__ bnst, const float* __restrict__ bng,
    const float* __restrict__ bnbe, const float* __restrict__ res,
    int fmode, float* __restrict__ part){
  int tap = blockIdx.y;
  int n = tapcnt[tap];
  int r0 = blockIdx.x*32;
  if (r0 >= n) return;
  __shared__ float Alt[96*34];
  __shared__ float Wlt[96*98];
  __shared__ int pqs[32];
  int tid = threadIdx.x;
  if (tid < 32){
    int r = r0 + tid;
    pqs[tid] = (r < n) ? ptlist[tap*NPTS + r] : -1;
  }
  __syncthreads();
  for (int idx4 = tid; idx4 < 2304; idx4 += 256){
    int ci = idx4/24, c4 = idx4 - ci*24;
    float4 w = ((const float4*)(Wc + ((long)tap*96 + ci)*96))[c4];
    float* d = &Wlt[ci*98 + c4*4];
    d[0]=w.x; d[1]=w.y; d[2]=w.z; d[3]=w.w;
  }
  for (int idx4 = tid; idx4 < 32*24; idx4 += 256){
    int ir = idx4/24, c4 = idx4 - ir*24;
    int pq = pqs[ir];
    float4 s4 = make_float4(0.f,0.f,0.f,0.f);
    if (pq >= 0){
      int q = pq & 0xFFFF;
      s4 = ((const float4*)(src + (long)q*CH))[c4];
      if (fmode){
        int c0 = c4*4;
        float vx = fmaxf((s4.x - bnst[(c0+0)*2])*bnst[(c0+0)*2+1]*bng[c0+0] + bnbe[c0+0], 0.f);
        float vy = fmaxf((s4.y - bnst[(c0+1)*2])*bnst[(c0+1)*2+1]*bng[c0+1] + bnbe[c0+1], 0.f);
        float vz = fmaxf((s4.z - bnst[(c0+2)*2])*bnst[(c0+2)*2+1]*bng[c0+2] + bnbe[c0+2], 0.f);
        float vw = fmaxf((s4.w - bnst[(c0+3)*2])*bnst[(c0+3)*2+1]*bng[c0+3] + bnbe[c0+3], 0.f);
        if (fmode == 2){
          const float* rr = res + (long)q*CH + c0;
          vx += rr[0]; vy += rr[1]; vz += rr[2]; vw += rr[3];
        }
        s4 = make_float4(vx,vy,vz,vw);
      }
    }
    int k0 = c4*4;
    Alt[(k0+0)*34 + ir] = s4.x;
    Alt[(k0+1)*34 + ir] = s4.y;
    Alt[(k0+2)*34 + ir] = s4.z;
    Alt[(k0+3)*34 + ir] = s4.w;
  }
  __syncthreads();
  int rp = tid >> 4, cg = tid & 15;
  int co0 = cg*6;
  int ra = 2*rp, rb = ra+1;
  float acc0[6]={0,0,0,0,0,0}, acc1[6]={0,0,0,0,0,0};
  for (int k=0;k<96;++k){
    float2 a  = *(const float2*)&Alt[k*34 + ra];
    float2 w0 = *(const float2*)&Wlt[k*98 + co0];
    float2 w1 = *(const float2*)&Wlt[k*98 + co0 + 2];
    float2 w2 = *(const float2*)&Wlt[k*98 + co0 + 4];
    acc0[0] = fmaf(a.x, w0.x, acc0[0]); acc1[0] = fmaf(a.y, w0.x, acc1[0]);
    acc0[1] = fmaf(a.x, w0.y, acc0[1]); acc1[1] = fmaf(a.y, w0.y, acc1[1]);
    acc0[2] = fmaf(a.x, w1.x, acc0[2]); acc1[2] = fmaf(a.y, w1.x, acc1[2]);
    acc0[3] = fmaf(a.x, w1.y, acc0[3]); acc1[3] = fmaf(a.y, w1.y, acc1[3]);
    acc0[4] = fmaf(a.x, w2.x, acc0[4]); acc1[4] = fmaf(a.y, w2.x, acc1[4]);
    acc0[5] = fmaf(a.x, w2.y, acc0[5]); acc1[5] = fmaf(a.y, w2.y, acc1[5]);
  }
  int pa = pqs[ra], pb2 = pqs[rb];
  if (pa >= 0){
    float* o = part + ((long)(pa>>16)*27 + tap)*CH + co0;
    #pragma unroll
    for (int j=0;j<6;++j) o[j] = acc0[j];
  }
  if (pb2 >= 0){
    float* o = part + ((long)(pb2>>16)*27 + tap)*CH + co0;
    #pragma unroll
    for (int j=0;j<6;++j) o[j] = acc1[j];
  }
}
__global__ void __launch_bounds__(256) k_conv_sum(const int* __restrict__ nbrtab,
                                                  const float* __restrict__ part,
                                                  float* __restrict__ out){
  int idx = blockIdx.x*256 + threadIdx.x;   // NPTS*24
  int p = idx/24, c4 = idx - p*24;
  const int* nt = nbrtab + p*27;
  float4 acc = make_float4(0.f,0.f,0.f,0.f);
  for (int tap=0; tap<27; ++tap){
    if (nt[tap] >= 0){
      float4 v = ((const float4*)part)[((long)p*27 + tap)*24 + c4];
      acc.x += v.x; acc.y += v.y; acc.z += v.z; acc.w += v.w;
    }
  }
  ((float4*)out)[idx] = acc;
}
// fallback: atomic scatter conv
__global__ void __launch_bounds__(256) k_conv_gemm_atomic(
    const float* __restrict__ src, const float* __restrict__ Wc,
    const int* __restrict__ tapcnt, const int* __restrict__ ptlist,
    float* __restrict__ out){
  int tap = blockIdx.y;
  int n = tapcnt[tap];
  int r0 = blockIdx.x*32;
  if (r0 >= n) return;
  __shared__ float Al[32*97];
  __shared__ float Wl[96*97];
  __shared__ int pqs[32];
  int tid = threadIdx.x;
  if (tid < 32){
    int r = r0 + tid;
    pqs[tid] = (r < n) ? ptlist[tap*NPTS + r] : -1;
  }
  __syncthreads();
  for (int idx4 = tid; idx4 < 2304; idx4 += 256){
    int ci = idx4/24, c4 = idx4 - ci*24;
    float4 w = ((const float4*)(Wc + ((long)tap*96 + ci)*96))[c4];
    float* d = &Wl[ci*97 + c4*4];
    d[0]=w.x; d[1]=w.y; d[2]=w.z; d[3]=w.w;
  }
  for (int idx4 = tid; idx4 < 32*24; idx4 += 256){
    int ir = idx4/24, c4 = idx4 - ir*24;
    int pq = pqs[ir];
    float4 s = make_float4(0.f,0.f,0.f,0.f);
    if (pq >= 0){
      int q = pq & 0xFFFF;
      s = ((const float4*)(src + (long)q*CH))[c4];
    }
    float* d = &Al[ir*97 + c4*4];
    d[0]=s.x; d[1]=s.y; d[2]=s.z; d[3]=s.w;
  }
  __syncthreads();
  int rp = tid >> 4, cg = tid & 15;
  int co0 = cg*6;
  int ra = 2*rp, rb = ra+1;
  float acc0[6]={0,0,0,0,0,0}, acc1[6]={0,0,0,0,0,0};
  for (int k=0;k<96;++k){
    float a0 = Al[ra*97+k], a1 = Al[rb*97+k];
    #pragma unroll
    for (int j=0;j<6;++j){
      float w = Wl[k*97+co0+j];
      acc0[j] = fmaf(a0, w, acc0[j]);
      acc1[j] = fmaf(a1, w, acc1[j]);
    }
  }
  int pa = pqs[ra], pb = pqs[rb];
  if (pa >= 0){
    float* o = out + (long)(pa>>16)*CH + co0;
    #pragma unroll
    for (int j=0;j<6;++j) atomicAdd(&o[j], acc0[j]);
  }
  if (pb >= 0){
    float* o = out + (long)(pb>>16)*CH + co0;
    #pragma unroll
    for (int j=0;j<6;++j) atomicAdd(&o[j], acc1[j]);
  }
}
// final: recompute fsd inline + bn2 + residual relu
__global__ void k_final(const float* __restrict__ c2, const float* __restrict__ st12,
                        const float* __restrict__ g2, const float* __restrict__ be2,
                        const float* __restrict__ tf, const float* __restrict__ st10,
                        const float* __restrict__ fg, const float* __restrict__ fbe,
                        const float* __restrict__ feat, float* __restrict__ out){
  int idx = blockIdx.x*blockDim.x + threadIdx.x;
  int c = idx % CH;
  float fsd = fmaxf((tf[idx] - st10[c*2])*st10[c*2+1]*fg[c] + fbe[c], 0.f) + feat[idx];
  float v = (c2[idx] - st12[c*2])*st12[c*2+1]*g2[c] + be2[c];
  out[idx] = fmaxf(v + fsd, 0.f);
}

// ---------- launcher ----------
extern "C" void kernel_launch(void* const* d_in, const int* in_sizes, int n_in,
                              void* d_out, int out_size, void* d_ws, size_t ws_size,
                              hipStream_t stream)
{
  const float* x      = (const float*)d_in[0];
  const int*   ind    = (const int*)  d_in[1];
  const float* fp_w   = (const float*)d_in[2];
  const float* fp_b   = (const float*)d_in[3];
  const float* fp_g   = (const float*)d_in[4];
  const float* fp_be  = (const float*)d_in[5];
  const float* att_w1 = (const float*)d_in[6];
  const float* att_b1 = (const float*)d_in[7];
  const float* att_w2 = (const float*)d_in[8];
  const float* att_b2 = (const float*)d_in[9];
  const float* ff_w1  = (const float*)d_in[10];
  const float* ff_b1  = (const float*)d_in[11];
  const float* ff_g   = (const float*)d_in[12];
  const float* ff_be  = (const float*)d_in[13];
  const float* ff_w2  = (const float*)d_in[14];
  const float* ff_b2  = (const float*)d_in[15];
  const float* sa_w1  = (const float*)d_in[16];
  const float* sa_b1  = (const float*)d_in[17];
  const float* sa_w2  = (const float*)d_in[18];
  const float* sa_b2  = (const float*)d_in[19];
  const float* fj_w1  = (const float*)d_in[20];
  const float* fj_b1  = (const float*)d_in[21];
  const float* fj_g   = (const float*)d_in[22];
  const float* fj_be  = (const float*)d_in[23];
  const float* fj_w2  = (const float*)d_in[24];
  const float* fj_b2  = (const float*)d_in[25];
  const float* proj_w = (const float*)d_in[26];
  const float* proj_g = (const float*)d_in[27];
  const float* proj_be= (const float*)d_in[28];
  const float* lw_w   = (const float*)d_in[29];
  const float* lw_g   = (const float*)d_in[30];
  const float* lw_be  = (const float*)d_in[31];
  const float* w_w    = (const float*)d_in[32];
  const float* adp_w  = (const float*)d_in[33];
  const float* fuse_w = (const float*)d_in[34];
  const float* fuse_g = (const float*)d_in[35];
  const float* fuse_be= (const float*)d_in[36];
  const float* conv1_w= (const float*)d_in[37];
  const float* bn1_g  = (const float*)d_in[38];
  const float* bn1_be = (const float*)d_in[39];
  const float* conv2_w= (const float*)d_in[40];
  const float* bn2_g  = (const float*)d_in[41];
  const float* bn2_be = (const float*)d_in[42];
  float* outp = (float*)d_out;
  (void)in_sizes; (void)n_in; (void)out_size;

  char* ws = (char*)d_ws;
  size_t off = 0;
  auto alloc = [&](size_t bytes)->size_t{
    off = (off + 255) & ~(size_t)255;
    size_t o = off; off += bytes; return o;
  };
  const size_t FNC = (size_t)NCELEM*4;
  size_t o_packed = alloc((size_t)NPTS*4);
  size_t o_start  = alloc(32);
  size_t o_ball   = alloc((size_t)NBALL*4);
  size_t o_dens   = alloc((size_t)NPTS*4);
  size_t o_lin    = alloc((size_t)NPTS*4);
  size_t o_t9     = alloc((size_t)NPTS*9*4);
  size_t o_enh    = alloc((size_t)NPTS*9*4);
  size_t o_gm     = alloc((size_t)NPTS*4);
  size_t o_gsz    = alloc((size_t)NPTS*3*4);
  size_t o_reps   = alloc(16*4);
  size_t o_bkt    = alloc((size_t)3*100*3*4);
  size_t o_seg    = alloc((size_t)3*NPTS*4);
  size_t o_table  = alloc((size_t)65536*4);
  size_t o_nbr    = alloc((size_t)NPTS*27*4);
  size_t o_ptlist = alloc((size_t)27*NPTS*4);
  size_t o_t64    = alloc((size_t)NPTS*64*4);
  size_t o_stats  = alloc((size_t)13*192*4);
  size_t o_htk    = alloc((size_t)3*HTSZ*8);
  size_t o_htv    = alloc((size_t)3*HTSZ*4);
  // --- contiguous zero region ---
  size_t o_S      = alloc(3*FNC);
  size_t o_E      = alloc(3*FNC);
  size_t o_F      = alloc(3*FNC);
  size_t o_cnt    = alloc((size_t)3*NPTS*4);
  size_t o_rank   = alloc((size_t)NPTS*4);
  size_t o_tapcnt = alloc(32*4);
  size_t o_done   = alloc(16);
  size_t o_maxenc = alloc(16*4);
  size_t zend = off;
  // --- big slots ---
  size_t o_T96 = alloc(FNC);
  size_t o_fu  = alloc(FNC);
  size_t o_feat= alloc(FNC);
  size_t o_tlw = alloc(3*FNC);
  size_t o_pw2 = alloc(3*FNC);
  size_t o_tp  = alloc(4*FNC);
  size_t o_agg = alloc(FNC);
  size_t o_tf  = alloc(FNC);
  size_t o_fsd = alloc(FNC);
  size_t o_c1  = alloc(FNC);
  size_t o_f1  = alloc(FNC);
  size_t o_c2  = alloc(FNC);
  size_t o_part = alloc((size_t)NPTS*27*CH*4);
  bool use_part = (off <= ws_size);

  float* stats = (float*)(ws + o_stats);
  long zcount = (long)((zend - o_S)/4);

  k_setup0<<<dim3(2048), dim3(256), 0, stream>>>((int*)(ws+o_S), zcount,
      (unsigned long long*)(ws+o_htk), (int*)(ws+o_htv), (int*)(ws+o_table), (int*)(ws+o_start));
  k_setup1<<<dim3(25), 256, 0, stream>>>(ind, (unsigned*)(ws+o_packed),
      (int*)(ws+o_start), (int*)(ws+o_table), (unsigned*)(ws+o_ball));

  // stage A
  k_mm<<<dim3(192,1), 256, 0, stream>>>(x, fp_w, fp_b, (float*)(ws+o_t9), 96, 9,
      0,0,0,0, nullptr,0, nullptr,nullptr,0, nullptr,nullptr,nullptr, nullptr, 0);
  k_stats<<<dim3(9,1), 256, 0, stream>>>((float*)(ws+o_t9), 0, 9, stats+0*192, 0);
  k_p_att_enh<<<dim3(24), 256, 0, stream>>>((float*)(ws+o_t9), stats+0*192, fp_g, fp_be,
      att_w1, att_b1, att_w2, att_b2, (float*)(ws+o_enh));

  k_mm<<<dim3(192,1), 256, 0, stream>>>((float*)(ws+o_enh), ff_w1, ff_b1, (float*)(ws+o_T96), 9, 96,
      0,0,0,0, nullptr,0, nullptr,nullptr,0, nullptr,nullptr,nullptr, nullptr, 0);
  k_stats<<<dim3(96,1), 256, 0, stream>>>((float*)(ws+o_T96), 0, 96, stats+1*192, 0);
  k_mm<<<dim3(192,1), 256, 0, stream>>>((float*)(ws+o_T96), ff_w2, ff_b2, (float*)(ws+o_fu), 96, 96,
      0,0,0,0, stats+1*192,0, ff_g, ff_be,0, nullptr,nullptr,nullptr, nullptr, 1);

  k_sem_feat<<<dim3(1536), 256, 0, stream>>>((float*)(ws+o_fu), x, sa_w1, sa_b1, sa_w2, sa_b2,
      (float*)(ws+o_feat));

  k_knn<<<dim3(1536), 256, 0, stream>>>((unsigned*)(ws+o_packed), (int*)(ws+o_table),
      (unsigned*)(ws+o_ball), (float*)(ws+o_dens), (float*)(ws+o_lin));

  k_mm<<<dim3(192,1), 256, 0, stream>>>((float*)(ws+o_feat), fj_w1, fj_b1, (float*)(ws+o_t64), 96, 64,
      0,0,0,0, nullptr,0, nullptr,nullptr,0, nullptr,nullptr,nullptr, nullptr, 0);
  k_stats<<<dim3(64,1), 256, 0, stream>>>((float*)(ws+o_t64), 0, 64, stats+2*192, 0);
  k_geo<<<dim3(24), 256, 0, stream>>>((float*)(ws+o_t64), stats+2*192, fj_g, fj_be, fj_w2, fj_b2,
      (float*)(ws+o_dens), (float*)(ws+o_lin), (float*)(ws+o_gsz), (float*)(ws+o_gm));

  k_rank<<<dim3(24,8), 256, 0, stream>>>((float*)(ws+o_gm), (int*)(ws+o_rank));
  k_scatter_reps<<<dim3(24), 256, 0, stream>>>((int*)(ws+o_rank), (float*)(ws+o_gsz),
      (float*)(ws+o_bkt), (int*)(ws+o_done), (float*)(ws+o_reps));

  k_seg_build<<<dim3(24,3), 256, 0, stream>>>(ind, (float*)(ws+o_reps), (int*)(ws+o_start),
      (unsigned long long*)(ws+o_htk), (int*)(ws+o_htv));
  k_seg_lookup<<<dim3(24,3), 256, 0, stream>>>(ind, (float*)(ws+o_reps), (int*)(ws+o_start),
      (unsigned long long*)(ws+o_htk), (int*)(ws+o_htv), (int*)(ws+o_seg), (int*)(ws+o_cnt));

  // branch pipelines (batched over 3)
  k_mm<<<dim3(192,3), 256, 0, stream>>>((float*)(ws+o_feat), lw_w, nullptr, (float*)(ws+o_tlw), 96, 96,
      0, 96*96, NCELEM, 0, nullptr,0, nullptr,nullptr,0, nullptr,nullptr,nullptr, nullptr, 0);
  k_stats<<<dim3(96,3), 256, 0, stream>>>((float*)(ws+o_tlw), NCELEM, 96, stats+3*192, 192);
  k_pw_accum<<<dim3(2304,3), 256, 0, stream>>>((float*)(ws+o_tlw), stats+3*192, lw_g, lw_be,
      (int*)(ws+o_seg), (float*)(ws+o_S));
  k_mm<<<dim3(192,3), 256, 0, stream>>>((float*)(ws+o_tlw), w_w, nullptr, (float*)(ws+o_pw2), 96, 96,
      NCELEM, 96*96, NCELEM, 0, stats+3*192,192, lw_g, lw_be,96,
      (float*)(ws+o_S), (int*)(ws+o_seg), (int*)(ws+o_cnt), (unsigned*)(ws+o_maxenc), 2);
  k_exp_accum<<<dim3(2304,3), 256, 0, stream>>>((float*)(ws+o_pw2), (unsigned*)(ws+o_maxenc),
      (int*)(ws+o_seg), (float*)(ws+o_E));
  k_mm<<<dim3(192,4), 256, 0, stream>>>((float*)(ws+o_feat), proj_w, nullptr, (float*)(ws+o_tp), 96, 96,
      0, 96*96, NCELEM, 0, nullptr,0, nullptr,nullptr,0, nullptr,nullptr,nullptr, nullptr, 0);
  k_stats<<<dim3(96,4), 256, 0, stream>>>((float*)(ws+o_tp), NCELEM, 96, stats+6*192, 192);
  k_pf_accum<<<dim3(2304,3), 256, 0, stream>>>((float*)(ws+o_tp), stats+6*192, proj_g, proj_be,
      (float*)(ws+o_pw2), (unsigned*)(ws+o_maxenc), (int*)(ws+o_seg), (float*)(ws+o_E), (float*)(ws+o_F));
  k_adp_agg<<<dim3(192), 256, 0, stream>>>((float*)(ws+o_feat), adp_w, (float*)(ws+o_F),
      (int*)(ws+o_seg), (float*)(ws+o_agg));

  // fuse gemm + stats(tf)
  k_mm_fuse<<<dim3(192), 256, 0, stream>>>((float*)(ws+o_tp) + (size_t)3*NCELEM, stats+9*192,
      proj_g + 3*96, proj_be + 3*96, (float*)(ws+o_agg), fuse_w, (float*)(ws+o_tf));
  k_stats<<<dim3(96,1), 256, 0, stream>>>((float*)(ws+o_tf), 0, 96, stats+10*192, 0);

  // sparse conv tail
  k_nbrlist<<<dim3(24), 256, 0, stream>>>(ind, (int*)(ws+o_table), (int*)(ws+o_nbr),
      (int*)(ws+o_tapcnt), (int*)(ws+o_ptlist));
  if (use_part){
    k_conv_gemm<<<dim3(192,27), 256, 0, stream>>>((float*)(ws+o_tf), conv1_w,
        (int*)(ws+o_tapcnt), (int*)(ws+o_ptlist),
        stats+10*192, fuse_g, fuse_be, (float*)(ws+o_feat), 2, (float*)(ws+o_part));
    k_conv_sum<<<dim3(NPTS*24/256), 256, 0, stream>>>((int*)(ws+o_nbr), (float*)(ws+o_part),
        (float*)(ws+o_c1));
    k_stats<<<dim3(96,1), 256, 0, stream>>>((float*)(ws+o_c1), 0, 96, stats+11*192, 0);
    k_conv_gemm<<<dim3(192,27), 256, 0, stream>>>((float*)(ws+o_c1), conv2_w,
        (int*)(ws+o_tapcnt), (int*)(ws+o_ptlist),
        stats+11*192, bn1_g, bn1_be, nullptr, 1, (float*)(ws+o_part));
    k_conv_sum<<<dim3(NPTS*24/256), 256, 0, stream>>>((int*)(ws+o_nbr), (float*)(ws+o_part),
        (float*)(ws+o_c2));
  } else {
    k_fused<<<dim3(2304), 256, 0, stream>>>((float*)(ws+o_tf), stats+10*192, fuse_g, fuse_be,
        (float*)(ws+o_feat), (float*)(ws+o_fsd));
    k_zero<<<dim3(2304), dim3(256), 0, stream>>>((int*)(ws+o_c1), NCELEM);
    k_conv_gemm_atomic<<<dim3(192,27), 256, 0, stream>>>((float*)(ws+o_fsd), conv1_w,
        (int*)(ws+o_tapcnt), (int*)(ws+o_ptlist), (float*)(ws+o_c1));
    k_stats<<<dim3(96,1), 256, 0, stream>>>((float*)(ws+o_c1), 0, 96, stats+11*192, 0);
    k_bnrelu<<<dim3(2304), 256, 0, stream>>>((float*)(ws+o_c1), stats+11*192, bn1_g, bn1_be,
        (float*)(ws+o_f1));
    k_zero<<<dim3(2304), dim3(256), 0, stream>>>((int*)(ws+o_c2), NCELEM);
    k_conv_gemm_atomic<<<dim3(192,27), 256, 0, stream>>>((float*)(ws+o_f1), conv2_w,
        (int*)(ws+o_tapcnt), (int*)(ws+o_ptlist), (float*)(ws+o_c2));
  }
  k_stats<<<dim3(96,1), 256, 0, stream>>>((float*)(ws+o_c2), 0, 96, stats+12*192, 0);
  k_final<<<dim3(2304), 256, 0, stream>>>((float*)(ws+o_c2), stats+12*192, bn2_g, bn2_be,
      (float*)(ws+o_tf), stats+10*192, fuse_g, fuse_be, (float*)(ws+o_feat), outp);
}